// Round 1
// baseline (1162.952 us; speedup 1.0000x reference)
//
#include <hip/hip_runtime.h>
#include <hip/hip_bf16.h>

#define S 768
#define CS 384
#define CP 128
#define E 16
#define PQ 4
#define PV 8
#define H 12
#define FDIM 2112          // H*(CP+E+PV*4)
#define OFF_PAIR 192       // H*E
#define OFF_PTS 1728       // +H*CP
#define OFF_NORM 2016      // +PV*H*3

typedef __hip_bfloat16 bf16;

__device__ __forceinline__ float b2f(bf16 x){ return __bfloat162float(x); }
__device__ __forceinline__ bf16 f2b(float x){ return __float2bfloat16(x); }
__device__ __forceinline__ float blo(unsigned u){ return __uint_as_float(u << 16); }
__device__ __forceinline__ float bhi(unsigned u){ return __uint_as_float(u & 0xffff0000u); }
__device__ __forceinline__ void up8(uint4 u, float* f){
  f[0]=blo(u.x); f[1]=bhi(u.x); f[2]=blo(u.y); f[3]=bhi(u.y);
  f[4]=blo(u.z); f[5]=bhi(u.z); f[6]=blo(u.w); f[7]=bhi(u.w);
}

// ---------------- kernel 1: projections + frame apply, 4 residues/block ---------
__global__ __launch_bounds__(256) void k_proj(
    const float* __restrict__ sr, const float* __restrict__ rot, const float* __restrict__ trans,
    const float* __restrict__ Wq, const float* __restrict__ Wk, const float* __restrict__ Wv,
    const float* __restrict__ Wqp, const float* __restrict__ Wkp, const float* __restrict__ Wvp,
    float* __restrict__ q, float* __restrict__ k, float* __restrict__ vT,
    float* __restrict__ lqp, float* __restrict__ lkp, float* __restrict__ lvpT)
{
  int s0 = blockIdx.x*4;
  __shared__ float srs[4][CS];
  __shared__ float Rs[4][9];
  __shared__ float ts[4][3];
  for (int x = threadIdx.x; x < 4*CS; x += 256) ((float*)srs)[x] = sr[(size_t)s0*CS + x];
  if (threadIdx.x < 36) ((float*)Rs)[threadIdx.x] = rot[(size_t)s0*9 + threadIdx.x];
  if (threadIdx.x >= 64 && threadIdx.x < 76) ((float*)ts)[threadIdx.x-64] = trans[(size_t)s0*3 + threadIdx.x-64];
  __syncthreads();

  for (int task = threadIdx.x; task < 768; task += 256){
    if (task < 576){
      int which = task / 192;
      int he = task - which*192;
      int h = he >> 4, e = he & 15;
      const float* W = (which==0 ? Wq : (which==1 ? Wk : Wv)) + (size_t)he*CS;
      const float4* W4 = (const float4*)W;
      float acc[4] = {0.f,0.f,0.f,0.f};
      for (int cc = 0; cc < CS/4; ++cc){
        float4 w = W4[cc];
        #pragma unroll
        for (int r = 0; r < 4; ++r){
          const float* sp = srs[r] + cc*4;
          acc[r] += w.x*sp[0] + w.y*sp[1] + w.z*sp[2] + w.w*sp[3];
        }
      }
      #pragma unroll
      for (int r = 0; r < 4; ++r){
        int s = s0 + r;
        if (which == 0)      q[((size_t)h*S + s)*E + e] = acc[r];
        else if (which == 1) k[((size_t)h*S + s)*E + e] = acc[r];
        else                 vT[((size_t)h*E + e)*S + s] = acc[r];
      }
    } else {
      int pt = task - 576;
      int h = pt >> 4, slot = pt & 15;
      int kind, p; const float* W;
      if (slot < 4)      { kind = 0; p = slot;     W = Wqp + (size_t)((h*PQ+p)*3)*CS; }
      else if (slot < 8) { kind = 1; p = slot - 4; W = Wkp + (size_t)((h*PQ+p)*3)*CS; }
      else               { kind = 2; p = slot - 8; W = Wvp + (size_t)((h*PV+p)*3)*CS; }
      const float4* W0 = (const float4*)W;
      const float4* W1 = (const float4*)(W + CS);
      const float4* W2 = (const float4*)(W + 2*CS);
      float a0[4] = {0,0,0,0}, a1[4] = {0,0,0,0}, a2[4] = {0,0,0,0};
      for (int cc = 0; cc < CS/4; ++cc){
        float4 w0 = W0[cc], w1 = W1[cc], w2 = W2[cc];
        #pragma unroll
        for (int r = 0; r < 4; ++r){
          const float* sp = srs[r] + cc*4;
          a0[r] += w0.x*sp[0] + w0.y*sp[1] + w0.z*sp[2] + w0.w*sp[3];
          a1[r] += w1.x*sp[0] + w1.y*sp[1] + w1.z*sp[2] + w1.w*sp[3];
          a2[r] += w2.x*sp[0] + w2.y*sp[1] + w2.z*sp[2] + w2.w*sp[3];
        }
      }
      #pragma unroll
      for (int r = 0; r < 4; ++r){
        int s = s0 + r;
        float l0 = Rs[r][0]*a0[r] + Rs[r][1]*a1[r] + Rs[r][2]*a2[r] + ts[r][0];
        float l1 = Rs[r][3]*a0[r] + Rs[r][4]*a1[r] + Rs[r][5]*a2[r] + ts[r][1];
        float l2 = Rs[r][6]*a0[r] + Rs[r][7]*a1[r] + Rs[r][8]*a2[r] + ts[r][2];
        if (kind == 0){ float* d = lqp + ((size_t)h*S + s)*12 + p*3; d[0]=l0; d[1]=l1; d[2]=l2; }
        else if (kind == 1){ float* d = lkp + ((size_t)h*S + s)*12 + p*3; d[0]=l0; d[1]=l1; d[2]=l2; }
        else {
          float* dst = lvpT + (size_t)h*24*S;
          dst[(size_t)(p*3+0)*S + s] = l0;
          dst[(size_t)(p*3+1)*S + s] = l1;
          dst[(size_t)(p*3+2)*S + s] = l2;
        }
      }
    }
  }
}

// ---------------- kernel 1b: w_pair[h][r] = sum_c Wb[h][c]*pair[r][c] -----------
// Tall-skinny streaming GEMV: one pair row (512 B) per thread, full occupancy
// (9216 waves), 16 loads in flight per thread. Memory-bound: 302 MB read + 28 MB
// fp32 write. Replaces k_attn's latency-bound phase A.
__global__ __launch_bounds__(256) void k_wpair(
    const float* __restrict__ pair, const float* __restrict__ Wb, float* __restrict__ wp)
{
  int r = blockIdx.x*256 + threadIdx.x;   // row in [0, S*S)
  const float4* prow = (const float4*)(pair + (size_t)r*CP);
  float acc[H];
  #pragma unroll
  for (int h = 0; h < H; ++h) acc[h] = 0.f;
  #pragma unroll
  for (int half = 0; half < 2; ++half){
    float4 buf[16];
    #pragma unroll
    for (int cc = 0; cc < 16; ++cc) buf[cc] = prow[half*16 + cc];
    #pragma unroll
    for (int h = 0; h < H; ++h){
      const float4* wb = (const float4*)(Wb + h*CP + half*64);  // uniform -> s_load
      float p0=0.f, p1=0.f, p2=0.f, p3=0.f;
      #pragma unroll
      for (int cc = 0; cc < 16; ++cc){
        float4 wv = wb[cc];
        p0 += wv.x*buf[cc].x; p1 += wv.y*buf[cc].y;
        p2 += wv.z*buf[cc].z; p3 += wv.w*buf[cc].w;
      }
      acc[h] += (p0+p1)+(p2+p3);
    }
  }
  #pragma unroll
  for (int h = 0; h < H; ++h) wp[(size_t)h*S*S + r] = acc[h];   // coalesced per h
}

// ---------------- kernel 2: logits (wp + single + frame) + softmax --------------
// block = residue i; thread t owns key rows j = t, t+256, t+512 for ALL 12 heads.
__global__ __launch_bounds__(256) void k_attn(
    const float* __restrict__ wp,
    const float* __restrict__ q, const float* __restrict__ k,
    const float* __restrict__ lqp, const float* __restrict__ lkp,
    const float* __restrict__ gamma, bf16* __restrict__ ab)
{
  int i = blockIdx.x;
  int t = threadIdx.x;
  int lane = t & 63;
  int w = t >> 6;

  float wreg[H][3];
  #pragma unroll
  for (int h = 0; h < H; ++h){
    const float* qrow = q   + ((size_t)h*S + i)*E;   // uniform -> s_load
    const float* lqr  = lqp + ((size_t)h*S + i)*12;  // uniform -> s_load
    const float* wrow = wp  + ((size_t)h*S + i)*S;
    float sf = -0.11785113019775793f * log1pf(__expf(gamma[h]));
    #pragma unroll
    for (int jj = 0; jj < 3; ++jj){
      int j = t + jj*256;
      const float* kr  = k   + ((size_t)h*S + j)*E;
      const float* lkr = lkp + ((size_t)h*S + j)*12;
      float d = 0.f;
      #pragma unroll
      for (int e = 0; e < E; ++e) d += qrow[e]*kr[e];
      float fr = 0.f;
      #pragma unroll
      for (int x = 0; x < 12; ++x){ float df = lqr[x] - lkr[x]; fr += df*df; }
      wreg[h][jj] = wrow[j] + 0.25f*d + sf*fr;
    }
  }

  // Softmax over j (768 values spread: 3 per thread x 256 threads) per head
  __shared__ __align__(16) float redm[H][4];
  __shared__ __align__(16) float redl[H][4];
  float m[H];
  #pragma unroll
  for (int h = 0; h < H; ++h){
    float v = fmaxf(fmaxf(wreg[h][0], wreg[h][1]), wreg[h][2]);
    #pragma unroll
    for (int mk = 1; mk < 64; mk <<= 1) v = fmaxf(v, __shfl_xor(v, mk));
    if (lane == 0) redm[h][w] = v;
  }
  __syncthreads();
  #pragma unroll
  for (int h = 0; h < H; ++h){
    float4 r = *(const float4*)redm[h];
    m[h] = fmaxf(fmaxf(r.x, r.y), fmaxf(r.z, r.w));
  }
  #pragma unroll
  for (int h = 0; h < H; ++h){
    wreg[h][0] = __expf(wreg[h][0] - m[h]);
    wreg[h][1] = __expf(wreg[h][1] - m[h]);
    wreg[h][2] = __expf(wreg[h][2] - m[h]);
    float v = wreg[h][0] + wreg[h][1] + wreg[h][2];
    #pragma unroll
    for (int mk = 1; mk < 64; mk <<= 1) v += __shfl_xor(v, mk);
    if (lane == 0) redl[h][w] = v;
  }
  __syncthreads();
  #pragma unroll
  for (int h = 0; h < H; ++h){
    float4 r = *(const float4*)redl[h];
    float inv = 1.f/((r.x + r.y) + (r.z + r.w));
    size_t base = ((size_t)h*S + i)*S + t;
    ab[base]       = f2b(wreg[h][0]*inv);
    ab[base + 256] = f2b(wreg[h][1]*inv);
    ab[base + 512] = f2b(wreg[h][2]*inv);
  }
}

// ---------------- kernel 3: a_sum over queries -> asumT[j*H+h] (fp32, atomic) ----
__global__ __launch_bounds__(256) void k_asum(const bf16* __restrict__ ab, float* __restrict__ asumT)
{
  int h  = blockIdx.x;
  int i0 = blockIdx.y * 24;
  int t  = threadIdx.x;
  float a0 = 0.f, a1 = 0.f, a2 = 0.f;
  for (int i = i0; i < i0 + 24; ++i){
    const bf16* row = ab + ((size_t)h*S + i)*S;
    a0 += b2f(row[t]);
    a1 += b2f(row[t + 256]);
    a2 += b2f(row[t + 512]);
  }
  atomicAdd(&asumT[(t      )*H + h], a0);
  atomicAdd(&asumT[(t + 256)*H + h], a1);
  atomicAdd(&asumT[(t + 512)*H + h], a2);
}

// ---------------- kernel 4: o_single + o_local -> o_global + norms --------------
__global__ __launch_bounds__(256) void k_out_sv(
    const bf16* __restrict__ ab, const float* __restrict__ vT, const float* __restrict__ lvpT,
    const float* __restrict__ rot, const float* __restrict__ trans, bf16* __restrict__ attnb)
{
  int h    = blockIdx.x / (S/4);
  int i0   = (blockIdx.x % (S/4))*4;
  int w    = threadIdx.x >> 6;
  int lane = threadIdx.x & 63;
  int i = i0 + w;
  const uint4* ar4 = (const uint4*)(ab + ((size_t)h*S + i)*S);  // 96 uint4 per row
  float acc = 0.f;
  const float* src = nullptr;
  if (lane < 16)      src = vT   + ((size_t)h*E  + lane)*S;
  else if (lane < 40) src = lvpT + ((size_t)h*24 + (lane-16))*S;
  if (src){
    for (int jb = 0; jb < S/8; ++jb){
      float af[8]; up8(ar4[jb], af);
      float4 s0 = *(const float4*)(src + jb*8);
      float4 s1 = *(const float4*)(src + jb*8 + 4);
      acc += af[0]*s0.x + af[1]*s0.y + af[2]*s0.z + af[3]*s0.w
           + af[4]*s1.x + af[5]*s1.y + af[6]*s1.z + af[7]*s1.w;
    }
  }
  __shared__ float ol[4][24];
  __shared__ float ogs[4][24];
  int pd = lane - 16;
  if (lane >= 16 && lane < 40) ol[w][pd] = acc;
  __syncthreads();
  if (lane < 16){
    attnb[(size_t)i*FDIM + h*E + lane] = f2b(acc);
  } else if (lane < 40){
    int p = pd/3, d = pd%3;
    float r0 = rot[(size_t)i*9 + 0 + d];
    float r1 = rot[(size_t)i*9 + 3 + d];
    float r2 = rot[(size_t)i*9 + 6 + d];
    float x0 = ol[w][p*3+0] - trans[i*3+0];
    float x1 = ol[w][p*3+1] - trans[i*3+1];
    float x2 = ol[w][p*3+2] - trans[i*3+2];
    float og = r0*x0 + r1*x1 + r2*x2;
    attnb[(size_t)i*FDIM + OFF_PTS + p*(H*3) + h*3 + d] = f2b(og);
    ogs[w][pd] = og;
  }
  __syncthreads();
  if (lane >= 16 && lane < 40 && (pd % 3) == 0){
    int p = pd/3;
    float g0 = ogs[w][p*3], g1 = ogs[w][p*3+1], g2 = ogs[w][p*3+2];
    attnb[(size_t)i*FDIM + OFF_NORM + p*H + h] = f2b(sqrtf(g0*g0 + g1*g1 + g2*g2));
  }
}

// ---------------- kernel 5: o_pair[i,h,c] = sum_k asum[h,k]*pair[i,k,c] ---------
// Widened to 8 waves/block (96 rows each) to double resident-wave count; the
// pair stream was grid-capped at 3072 waves before. LDS partials 48 KB.
__global__ __launch_bounds__(512) void k_opair(const float* __restrict__ pair,
                                               const float* __restrict__ asumT,
                                               bf16* __restrict__ attnb)
{
  int i  = blockIdx.x;
  int t  = threadIdx.x;
  int c2 = t & 63;
  int g  = __builtin_amdgcn_readfirstlane(t >> 6);   // wave id 0..7, uniform
  float accx[H], accy[H];
  #pragma unroll
  for (int h = 0; h < H; ++h){ accx[h] = 0.f; accy[h] = 0.f; }
  const float2* prow = (const float2*)(pair + (size_t)i*S*CP) + c2;
  for (int kk = 0; kk < 96; ++kk){
    int kj = g*96 + kk;
    float2 pv = prow[(size_t)kj*64];
    const float* ap = asumT + kj*H;    // uniform -> s_load
    #pragma unroll
    for (int h = 0; h < H; ++h){
      accx[h] += ap[h]*pv.x;
      accy[h] += ap[h]*pv.y;
    }
  }
  __shared__ float part[8][H][CP];   // 48 KB
  #pragma unroll
  for (int h = 0; h < H; ++h)
    ((float2*)part[g][h])[c2] = make_float2(accx[h], accy[h]);
  __syncthreads();
  if (t < CP){
    #pragma unroll
    for (int h = 0; h < H; ++h){
      float s = part[0][h][t] + part[1][h][t] + part[2][h][t] + part[3][h][t]
              + part[4][h][t] + part[5][h][t] + part[6][h][t] + part[7][h][t];
      attnb[(size_t)i*FDIM + OFF_PAIR + h*CP + t] = f2b(s);
    }
  }
}

// ---------------- kernel 6: out = attn @ Wo^T + bo (4 rows/block) ---------------
__global__ __launch_bounds__(384) void k_final(const bf16* __restrict__ attnb,
                                               const float* __restrict__ Wo,
                                               const float* __restrict__ bo,
                                               float* __restrict__ out)
{
  int i0 = blockIdx.x*4;
  int o  = threadIdx.x;
  const float4* wrow = (const float4*)(Wo + (size_t)o*FDIM);   // 528 float4
  const unsigned* a0 = (const unsigned*)(attnb + (size_t)i0*FDIM);  // uniform
  const unsigned* a1 = a0 + FDIM/2;
  const unsigned* a2 = a1 + FDIM/2;
  const unsigned* a3 = a2 + FDIM/2;
  float c0=0.f, c1=0.f, c2=0.f, c3=0.f;
  for (int cc = 0; cc < FDIM/4; ++cc){
    float4 wv = wrow[cc];
    unsigned u;
    u = a0[cc*2]; c0 += wv.x*blo(u)+wv.y*bhi(u); u = a0[cc*2+1]; c0 += wv.z*blo(u)+wv.w*bhi(u);
    u = a1[cc*2]; c1 += wv.x*blo(u)+wv.y*bhi(u); u = a1[cc*2+1]; c1 += wv.z*blo(u)+wv.w*bhi(u);
    u = a2[cc*2]; c2 += wv.x*blo(u)+wv.y*bhi(u); u = a2[cc*2+1]; c2 += wv.z*blo(u)+wv.w*bhi(u);
    u = a3[cc*2]; c3 += wv.x*blo(u)+wv.y*bhi(u); u = a3[cc*2+1]; c3 += wv.z*blo(u)+wv.w*bhi(u);
  }
  float b = bo[o];
  out[(size_t)(i0+0)*CS + o] = c0 + b;
  out[(size_t)(i0+1)*CS + o] = c1 + b;
  out[(size_t)(i0+2)*CS + o] = c2 + b;
  out[(size_t)(i0+3)*CS + o] = c3 + b;
}

extern "C" void kernel_launch(void* const* d_in, const int* in_sizes, int n_in,
                              void* d_out, int out_size, void* d_ws, size_t ws_size,
                              hipStream_t stream)
{
  const float* sr    = (const float*)d_in[0];
  const float* pair  = (const float*)d_in[1];
  const float* rot   = (const float*)d_in[2];
  const float* trans = (const float*)d_in[3];
  const float* Wq    = (const float*)d_in[4];
  const float* Wk    = (const float*)d_in[5];
  const float* Wv    = (const float*)d_in[6];
  const float* Wqp   = (const float*)d_in[7];
  const float* Wkp   = (const float*)d_in[8];
  const float* Wvp   = (const float*)d_in[9];
  const float* Wb    = (const float*)d_in[10];
  const float* Wo    = (const float*)d_in[11];
  const float* bo    = (const float*)d_in[12];
  const float* gamma = (const float*)d_in[13];

  // workspace layout (float units); total ~12.32M floats = 49.3 MB
  float* ws    = (float*)d_ws;
  float* q     = ws;                  // 147456
  float* k     = q     + 147456;      // 147456
  float* vT    = k     + 147456;      // 147456 [h][e][s]
  float* lqp   = vT    + 147456;      // 110592
  float* lkp   = lqp   + 110592;      // 110592
  float* lvpT  = lkp   + 110592;      // 221184 [h][pd][s]
  float* asumT = lvpT  + 221184;      // 9216  [j][h]
  bf16*  ab    = (bf16*)(asumT + 9216);              // H*S*S bf16
  bf16*  attnb = (bf16*)(asumT + 9216 + 3538944);    // S*FDIM bf16
  float* wp    = asumT + 9216 + 3538944 + 811008;    // H*S*S fp32 logits
  float* out = (float*)d_out;

  hipMemsetAsync(asumT, 0, (size_t)S*H*sizeof(float), stream);
  k_proj  <<<S/4,          256, 0, stream>>>(sr, rot, trans, Wq, Wk, Wv, Wqp, Wkp, Wvp,
                                             q, k, vT, lqp, lkp, lvpT);
  k_wpair <<<(S*S)/256,    256, 0, stream>>>(pair, Wb, wp);
  k_attn  <<<S,            256, 0, stream>>>(wp, q, k, lqp, lkp, gamma, ab);
  k_asum  <<<dim3(H, 32),  256, 0, stream>>>(ab, asumT);
  k_out_sv<<<H*(S/4),      256, 0, stream>>>(ab, vT, lvpT, rot, trans, attnb);
  k_opair <<<S,            512, 0, stream>>>(pair, asumT, attnb);
  k_final <<<S/4,          384, 0, stream>>>(attnb, Wo, bo, out);
}

// Round 2
// 920.104 us; speedup vs baseline: 1.2639x; 1.2639x over previous
//
#include <hip/hip_runtime.h>
#include <hip/hip_bf16.h>

#define S 768
#define CS 384
#define CP 128
#define E 16
#define PQ 4
#define PV 8
#define H 12
#define FDIM 2112          // H*(CP+E+PV*4)
#define OFF_PAIR 192       // H*E
#define OFF_PTS 1728       // +H*CP
#define OFF_NORM 2016      // +PV*H*3

typedef __hip_bfloat16 bf16;

__device__ __forceinline__ float b2f(bf16 x){ return __bfloat162float(x); }
__device__ __forceinline__ bf16 f2b(float x){ return __float2bfloat16(x); }
__device__ __forceinline__ float blo(unsigned u){ return __uint_as_float(u << 16); }
__device__ __forceinline__ float bhi(unsigned u){ return __uint_as_float(u & 0xffff0000u); }
__device__ __forceinline__ void up8(uint4 u, float* f){
  f[0]=blo(u.x); f[1]=bhi(u.x); f[2]=blo(u.y); f[3]=bhi(u.y);
  f[4]=blo(u.z); f[5]=bhi(u.z); f[6]=blo(u.w); f[7]=bhi(u.w);
}

// ---------------- kernel 1: projections + frame apply, 4 residues/block ---------
__global__ __launch_bounds__(256) void k_proj(
    const float* __restrict__ sr, const float* __restrict__ rot, const float* __restrict__ trans,
    const float* __restrict__ Wq, const float* __restrict__ Wk, const float* __restrict__ Wv,
    const float* __restrict__ Wqp, const float* __restrict__ Wkp, const float* __restrict__ Wvp,
    float* __restrict__ q, float* __restrict__ k, float* __restrict__ vT,
    float* __restrict__ lqp, float* __restrict__ lkp, float* __restrict__ lvpT)
{
  int s0 = blockIdx.x*4;
  __shared__ float srs[4][CS];
  __shared__ float Rs[4][9];
  __shared__ float ts[4][3];
  for (int x = threadIdx.x; x < 4*CS; x += 256) ((float*)srs)[x] = sr[(size_t)s0*CS + x];
  if (threadIdx.x < 36) ((float*)Rs)[threadIdx.x] = rot[(size_t)s0*9 + threadIdx.x];
  if (threadIdx.x >= 64 && threadIdx.x < 76) ((float*)ts)[threadIdx.x-64] = trans[(size_t)s0*3 + threadIdx.x-64];
  __syncthreads();

  for (int task = threadIdx.x; task < 768; task += 256){
    if (task < 576){
      int which = task / 192;
      int he = task - which*192;
      int h = he >> 4, e = he & 15;
      const float* W = (which==0 ? Wq : (which==1 ? Wk : Wv)) + (size_t)he*CS;
      const float4* W4 = (const float4*)W;
      float acc[4] = {0.f,0.f,0.f,0.f};
      for (int cc = 0; cc < CS/4; ++cc){
        float4 w = W4[cc];
        #pragma unroll
        for (int r = 0; r < 4; ++r){
          const float* sp = srs[r] + cc*4;
          acc[r] += w.x*sp[0] + w.y*sp[1] + w.z*sp[2] + w.w*sp[3];
        }
      }
      #pragma unroll
      for (int r = 0; r < 4; ++r){
        int s = s0 + r;
        if (which == 0)      q[((size_t)h*S + s)*E + e] = acc[r];
        else if (which == 1) k[((size_t)h*S + s)*E + e] = acc[r];
        else                 vT[((size_t)h*E + e)*S + s] = acc[r];
      }
    } else {
      int pt = task - 576;
      int h = pt >> 4, slot = pt & 15;
      int kind, p; const float* W;
      if (slot < 4)      { kind = 0; p = slot;     W = Wqp + (size_t)((h*PQ+p)*3)*CS; }
      else if (slot < 8) { kind = 1; p = slot - 4; W = Wkp + (size_t)((h*PQ+p)*3)*CS; }
      else               { kind = 2; p = slot - 8; W = Wvp + (size_t)((h*PV+p)*3)*CS; }
      const float4* W0 = (const float4*)W;
      const float4* W1 = (const float4*)(W + CS);
      const float4* W2 = (const float4*)(W + 2*CS);
      float a0[4] = {0,0,0,0}, a1[4] = {0,0,0,0}, a2[4] = {0,0,0,0};
      for (int cc = 0; cc < CS/4; ++cc){
        float4 w0 = W0[cc], w1 = W1[cc], w2 = W2[cc];
        #pragma unroll
        for (int r = 0; r < 4; ++r){
          const float* sp = srs[r] + cc*4;
          a0[r] += w0.x*sp[0] + w0.y*sp[1] + w0.z*sp[2] + w0.w*sp[3];
          a1[r] += w1.x*sp[0] + w1.y*sp[1] + w1.z*sp[2] + w1.w*sp[3];
          a2[r] += w2.x*sp[0] + w2.y*sp[1] + w2.z*sp[2] + w2.w*sp[3];
        }
      }
      #pragma unroll
      for (int r = 0; r < 4; ++r){
        int s = s0 + r;
        float l0 = Rs[r][0]*a0[r] + Rs[r][1]*a1[r] + Rs[r][2]*a2[r] + ts[r][0];
        float l1 = Rs[r][3]*a0[r] + Rs[r][4]*a1[r] + Rs[r][5]*a2[r] + ts[r][1];
        float l2 = Rs[r][6]*a0[r] + Rs[r][7]*a1[r] + Rs[r][8]*a2[r] + ts[r][2];
        if (kind == 0){ float* d = lqp + ((size_t)h*S + s)*12 + p*3; d[0]=l0; d[1]=l1; d[2]=l2; }
        else if (kind == 1){ float* d = lkp + ((size_t)h*S + s)*12 + p*3; d[0]=l0; d[1]=l1; d[2]=l2; }
        else {
          float* dst = lvpT + (size_t)h*24*S;
          dst[(size_t)(p*3+0)*S + s] = l0;
          dst[(size_t)(p*3+1)*S + s] = l1;
          dst[(size_t)(p*3+2)*S + s] = l2;
        }
      }
    }
  }
}

// ---------------- kernel 1b: w_pair[h][r] = sum_c Wb[h][c]*pair[r][c] -----------
// Tall-skinny streaming GEMV: one pair row (512 B) per thread, full occupancy
// (9216 waves). Memory-bound: 302 MB read + 28 MB fp32 write.
__global__ __launch_bounds__(256) void k_wpair(
    const float* __restrict__ pair, const float* __restrict__ Wb, float* __restrict__ wp)
{
  int r = blockIdx.x*256 + threadIdx.x;   // row in [0, S*S)
  const float4* prow = (const float4*)(pair + (size_t)r*CP);
  float acc[H];
  #pragma unroll
  for (int h = 0; h < H; ++h) acc[h] = 0.f;
  #pragma unroll
  for (int half = 0; half < 2; ++half){
    float4 buf[16];
    #pragma unroll
    for (int cc = 0; cc < 16; ++cc) buf[cc] = prow[half*16 + cc];
    #pragma unroll
    for (int h = 0; h < H; ++h){
      const float4* wb = (const float4*)(Wb + h*CP + half*64);  // uniform -> s_load
      float p0=0.f, p1=0.f, p2=0.f, p3=0.f;
      #pragma unroll
      for (int cc = 0; cc < 16; ++cc){
        float4 wv = wb[cc];
        p0 += wv.x*buf[cc].x; p1 += wv.y*buf[cc].y;
        p2 += wv.z*buf[cc].z; p3 += wv.w*buf[cc].w;
      }
      acc[h] += (p0+p1)+(p2+p3);
    }
  }
  #pragma unroll
  for (int h = 0; h < H; ++h) wp[(size_t)h*S*S + r] = acc[h];   // coalesced per h
}

// ---------------- kernel 2: logits (wp + single + frame) + softmax --------------
// One WAVE owns one full head-row: block = (residue i, head-group hg of 4 heads),
// wave w computes head hg*4+w over all 768 keys (12 j's per lane). Logits go to
// LDS (no big register arrays -> no spill); softmax is pure intra-wave shfl.
// 2304 blocks x 4 waves = 9216 waves -> not grid-capped.
__global__ __launch_bounds__(256) void k_attn(
    const float* __restrict__ wp,
    const float* __restrict__ q, const float* __restrict__ k,
    const float* __restrict__ lqp, const float* __restrict__ lkp,
    const float* __restrict__ gamma, bf16* __restrict__ ab)
{
  int i    = blockIdx.x / 3;
  int hg   = blockIdx.x % 3;
  int lane = threadIdx.x & 63;
  int w    = __builtin_amdgcn_readfirstlane(threadIdx.x >> 6);  // wave id, uniform
  int h    = hg*4 + w;

  __shared__ float lgs[4][S];   // 12 KB

  const float* qrow = q   + ((size_t)h*S + i)*E;   // wave-uniform -> s_load
  const float* lqr  = lqp + ((size_t)h*S + i)*12;  // wave-uniform -> s_load
  const float* wrow = wp  + ((size_t)h*S + i)*S;
  float sf = -0.11785113019775793f * log1pf(__expf(gamma[h]));

  float qv[E];
  #pragma unroll
  for (int e = 0; e < E; ++e) qv[e] = qrow[e];
  float lq[12];
  #pragma unroll
  for (int x = 0; x < 12; ++x) lq[x] = lqr[x];

  float mloc = -1e30f;
  #pragma unroll 3
  for (int jj = 0; jj < 12; ++jj){
    int j = lane + jj*64;
    const float4* kr4 = (const float4*)(k   + ((size_t)h*S + j)*E);
    const float4* lk4 = (const float4*)(lkp + ((size_t)h*S + j)*12);
    float4 k0 = kr4[0], k1 = kr4[1], k2 = kr4[2], k3 = kr4[3];
    float4 p0 = lk4[0], p1 = lk4[1], p2 = lk4[2];
    float d = qv[0]*k0.x + qv[1]*k0.y + qv[2]*k0.z + qv[3]*k0.w
            + qv[4]*k1.x + qv[5]*k1.y + qv[6]*k1.z + qv[7]*k1.w
            + qv[8]*k2.x + qv[9]*k2.y + qv[10]*k2.z + qv[11]*k2.w
            + qv[12]*k3.x + qv[13]*k3.y + qv[14]*k3.z + qv[15]*k3.w;
    float d0 = lq[0]-p0.x, d1 = lq[1]-p0.y, d2  = lq[2]-p0.z,  d3  = lq[3]-p0.w;
    float d4 = lq[4]-p1.x, d5 = lq[5]-p1.y, d6  = lq[6]-p1.z,  d7  = lq[7]-p1.w;
    float d8 = lq[8]-p2.x, d9 = lq[9]-p2.y, d10 = lq[10]-p2.z, d11 = lq[11]-p2.w;
    float fr = d0*d0 + d1*d1 + d2*d2 + d3*d3 + d4*d4 + d5*d5
             + d6*d6 + d7*d7 + d8*d8 + d9*d9 + d10*d10 + d11*d11;
    float lg = wrow[j] + 0.25f*d + sf*fr;
    lgs[w][j] = lg;
    mloc = fmaxf(mloc, lg);
  }
  #pragma unroll
  for (int mk = 1; mk < 64; mk <<= 1) mloc = fmaxf(mloc, __shfl_xor(mloc, mk));

  float sum = 0.f;
  #pragma unroll 3
  for (int jj = 0; jj < 12; ++jj){
    int j = lane + jj*64;
    float v = __expf(lgs[w][j] - mloc);
    lgs[w][j] = v;
    sum += v;
  }
  #pragma unroll
  for (int mk = 1; mk < 64; mk <<= 1) sum += __shfl_xor(sum, mk);
  float inv = 1.f/sum;

  size_t base = ((size_t)h*S + i)*S;
  #pragma unroll 3
  for (int jj = 0; jj < 12; ++jj){
    int j = lane + jj*64;
    ab[base + j] = f2b(lgs[w][j]*inv);
  }
}

// ---------------- kernel 3: a_sum over queries -> asumT[j*H+h] (fp32, atomic) ----
__global__ __launch_bounds__(256) void k_asum(const bf16* __restrict__ ab, float* __restrict__ asumT)
{
  int h  = blockIdx.x;
  int i0 = blockIdx.y * 24;
  int t  = threadIdx.x;
  float a0 = 0.f, a1 = 0.f, a2 = 0.f;
  for (int i = i0; i < i0 + 24; ++i){
    const bf16* row = ab + ((size_t)h*S + i)*S;
    a0 += b2f(row[t]);
    a1 += b2f(row[t + 256]);
    a2 += b2f(row[t + 512]);
  }
  atomicAdd(&asumT[(t      )*H + h], a0);
  atomicAdd(&asumT[(t + 256)*H + h], a1);
  atomicAdd(&asumT[(t + 512)*H + h], a2);
}

// ---------------- kernel 4: o_single + o_local -> o_global + norms --------------
__global__ __launch_bounds__(256) void k_out_sv(
    const bf16* __restrict__ ab, const float* __restrict__ vT, const float* __restrict__ lvpT,
    const float* __restrict__ rot, const float* __restrict__ trans, bf16* __restrict__ attnb)
{
  int h    = blockIdx.x / (S/4);
  int i0   = (blockIdx.x % (S/4))*4;
  int w    = threadIdx.x >> 6;
  int lane = threadIdx.x & 63;
  int i = i0 + w;
  const uint4* ar4 = (const uint4*)(ab + ((size_t)h*S + i)*S);  // 96 uint4 per row
  float acc = 0.f;
  const float* src = nullptr;
  if (lane < 16)      src = vT   + ((size_t)h*E  + lane)*S;
  else if (lane < 40) src = lvpT + ((size_t)h*24 + (lane-16))*S;
  if (src){
    for (int jb = 0; jb < S/8; ++jb){
      float af[8]; up8(ar4[jb], af);
      float4 s0 = *(const float4*)(src + jb*8);
      float4 s1 = *(const float4*)(src + jb*8 + 4);
      acc += af[0]*s0.x + af[1]*s0.y + af[2]*s0.z + af[3]*s0.w
           + af[4]*s1.x + af[5]*s1.y + af[6]*s1.z + af[7]*s1.w;
    }
  }
  __shared__ float ol[4][24];
  __shared__ float ogs[4][24];
  int pd = lane - 16;
  if (lane >= 16 && lane < 40) ol[w][pd] = acc;
  __syncthreads();
  if (lane < 16){
    attnb[(size_t)i*FDIM + h*E + lane] = f2b(acc);
  } else if (lane < 40){
    int p = pd/3, d = pd%3;
    float r0 = rot[(size_t)i*9 + 0 + d];
    float r1 = rot[(size_t)i*9 + 3 + d];
    float r2 = rot[(size_t)i*9 + 6 + d];
    float x0 = ol[w][p*3+0] - trans[i*3+0];
    float x1 = ol[w][p*3+1] - trans[i*3+1];
    float x2 = ol[w][p*3+2] - trans[i*3+2];
    float og = r0*x0 + r1*x1 + r2*x2;
    attnb[(size_t)i*FDIM + OFF_PTS + p*(H*3) + h*3 + d] = f2b(og);
    ogs[w][pd] = og;
  }
  __syncthreads();
  if (lane >= 16 && lane < 40 && (pd % 3) == 0){
    int p = pd/3;
    float g0 = ogs[w][p*3], g1 = ogs[w][p*3+1], g2 = ogs[w][p*3+2];
    attnb[(size_t)i*FDIM + OFF_NORM + p*H + h] = f2b(sqrtf(g0*g0 + g1*g1 + g2*g2));
  }
}

// ---------------- kernel 5: o_pair[i,h,c] = sum_k asum[h,k]*pair[i,k,c] ---------
__global__ __launch_bounds__(512) void k_opair(const float* __restrict__ pair,
                                               const float* __restrict__ asumT,
                                               bf16* __restrict__ attnb)
{
  int i  = blockIdx.x;
  int t  = threadIdx.x;
  int c2 = t & 63;
  int g  = __builtin_amdgcn_readfirstlane(t >> 6);   // wave id 0..7, uniform
  float accx[H], accy[H];
  #pragma unroll
  for (int h = 0; h < H; ++h){ accx[h] = 0.f; accy[h] = 0.f; }
  const float2* prow = (const float2*)(pair + (size_t)i*S*CP) + c2;
  for (int kk = 0; kk < 96; ++kk){
    int kj = g*96 + kk;
    float2 pv = prow[(size_t)kj*64];
    const float* ap = asumT + kj*H;    // uniform -> s_load
    #pragma unroll
    for (int h = 0; h < H; ++h){
      accx[h] += ap[h]*pv.x;
      accy[h] += ap[h]*pv.y;
    }
  }
  __shared__ float part[8][H][CP];   // 48 KB
  #pragma unroll
  for (int h = 0; h < H; ++h)
    ((float2*)part[g][h])[c2] = make_float2(accx[h], accy[h]);
  __syncthreads();
  if (t < CP){
    #pragma unroll
    for (int h = 0; h < H; ++h){
      float s = part[0][h][t] + part[1][h][t] + part[2][h][t] + part[3][h][t]
              + part[4][h][t] + part[5][h][t] + part[6][h][t] + part[7][h][t];
      attnb[(size_t)i*FDIM + OFF_PAIR + h*CP + t] = f2b(s);
    }
  }
}

// ---------------- kernel 6: out = attn @ Wo^T + bo (4 rows/block) ---------------
__global__ __launch_bounds__(384) void k_final(const bf16* __restrict__ attnb,
                                               const float* __restrict__ Wo,
                                               const float* __restrict__ bo,
                                               float* __restrict__ out)
{
  int i0 = blockIdx.x*4;
  int o  = threadIdx.x;
  const float4* wrow = (const float4*)(Wo + (size_t)o*FDIM);   // 528 float4
  const unsigned* a0 = (const unsigned*)(attnb + (size_t)i0*FDIM);  // uniform
  const unsigned* a1 = a0 + FDIM/2;
  const unsigned* a2 = a1 + FDIM/2;
  const unsigned* a3 = a2 + FDIM/2;
  float c0=0.f, c1=0.f, c2=0.f, c3=0.f;
  for (int cc = 0; cc < FDIM/4; ++cc){
    float4 wv = wrow[cc];
    unsigned u;
    u = a0[cc*2]; c0 += wv.x*blo(u)+wv.y*bhi(u); u = a0[cc*2+1]; c0 += wv.z*blo(u)+wv.w*bhi(u);
    u = a1[cc*2]; c1 += wv.x*blo(u)+wv.y*bhi(u); u = a1[cc*2+1]; c1 += wv.z*blo(u)+wv.w*bhi(u);
    u = a2[cc*2]; c2 += wv.x*blo(u)+wv.y*bhi(u); u = a2[cc*2+1]; c2 += wv.z*blo(u)+wv.w*bhi(u);
    u = a3[cc*2]; c3 += wv.x*blo(u)+wv.y*bhi(u); u = a3[cc*2+1]; c3 += wv.z*blo(u)+wv.w*bhi(u);
  }
  float b = bo[o];
  out[(size_t)(i0+0)*CS + o] = c0 + b;
  out[(size_t)(i0+1)*CS + o] = c1 + b;
  out[(size_t)(i0+2)*CS + o] = c2 + b;
  out[(size_t)(i0+3)*CS + o] = c3 + b;
}

extern "C" void kernel_launch(void* const* d_in, const int* in_sizes, int n_in,
                              void* d_out, int out_size, void* d_ws, size_t ws_size,
                              hipStream_t stream)
{
  const float* sr    = (const float*)d_in[0];
  const float* pair  = (const float*)d_in[1];
  const float* rot   = (const float*)d_in[2];
  const float* trans = (const float*)d_in[3];
  const float* Wq    = (const float*)d_in[4];
  const float* Wk    = (const float*)d_in[5];
  const float* Wv    = (const float*)d_in[6];
  const float* Wqp   = (const float*)d_in[7];
  const float* Wkp   = (const float*)d_in[8];
  const float* Wvp   = (const float*)d_in[9];
  const float* Wb    = (const float*)d_in[10];
  const float* Wo    = (const float*)d_in[11];
  const float* bo    = (const float*)d_in[12];
  const float* gamma = (const float*)d_in[13];

  // workspace layout (float units); total ~12.32M floats = 49.3 MB
  float* ws    = (float*)d_ws;
  float* q     = ws;                  // 147456
  float* k     = q     + 147456;      // 147456
  float* vT    = k     + 147456;      // 147456 [h][e][s]
  float* lqp   = vT    + 147456;      // 110592
  float* lkp   = lqp   + 110592;      // 110592
  float* lvpT  = lkp   + 110592;      // 221184 [h][pd][s]
  float* asumT = lvpT  + 221184;      // 9216  [j][h]
  bf16*  ab    = (bf16*)(asumT + 9216);              // H*S*S bf16
  bf16*  attnb = (bf16*)(asumT + 9216 + 3538944);    // S*FDIM bf16
  float* wp    = asumT + 9216 + 3538944 + 811008;    // H*S*S fp32 logits
  float* out = (float*)d_out;

  hipMemsetAsync(asumT, 0, (size_t)S*H*sizeof(float), stream);
  k_proj  <<<S/4,          256, 0, stream>>>(sr, rot, trans, Wq, Wk, Wv, Wqp, Wkp, Wvp,
                                             q, k, vT, lqp, lkp, lvpT);
  k_wpair <<<(S*S)/256,    256, 0, stream>>>(pair, Wb, wp);
  k_attn  <<<S*3,          256, 0, stream>>>(wp, q, k, lqp, lkp, gamma, ab);
  k_asum  <<<dim3(H, 32),  256, 0, stream>>>(ab, asumT);
  k_out_sv<<<H*(S/4),      256, 0, stream>>>(ab, vT, lvpT, rot, trans, attnb);
  k_opair <<<S,            512, 0, stream>>>(pair, asumT, attnb);
  k_final <<<S/4,          384, 0, stream>>>(attnb, Wo, bo, out);
}

// Round 3
// 911.202 us; speedup vs baseline: 1.2763x; 1.0098x over previous
//
#include <hip/hip_runtime.h>
#include <hip/hip_bf16.h>

#define S 768
#define CS 384
#define CP 128
#define E 16
#define PQ 4
#define PV 8
#define H 12
#define FDIM 2112          // H*(CP+E+PV*4)
#define OFF_PAIR 192       // H*E
#define OFF_PTS 1728       // +H*CP
#define OFF_NORM 2016      // +PV*H*3

typedef __hip_bfloat16 bf16;

__device__ __forceinline__ float b2f(bf16 x){ return __bfloat162float(x); }
__device__ __forceinline__ bf16 f2b(float x){ return __float2bfloat16(x); }
__device__ __forceinline__ float blo(unsigned u){ return __uint_as_float(u << 16); }
__device__ __forceinline__ float bhi(unsigned u){ return __uint_as_float(u & 0xffff0000u); }
__device__ __forceinline__ void up8(uint4 u, float* f){
  f[0]=blo(u.x); f[1]=bhi(u.x); f[2]=blo(u.y); f[3]=bhi(u.y);
  f[4]=blo(u.z); f[5]=bhi(u.z); f[6]=blo(u.w); f[7]=bhi(u.w);
}

// ---------------- kernel 1: projections + frame apply, 2 residues/block ---------
// 384 blocks x 4 waves = 1536 waves (6/CU) vs previous 768 (3/CU): latency-bound
// serial W-row loops now have 2x the waves to hide behind. W L2 traffic ~680 MB
// (~19 us of L2 BW) -- cheap.
__global__ __launch_bounds__(256) void k_proj(
    const float* __restrict__ sr, const float* __restrict__ rot, const float* __restrict__ trans,
    const float* __restrict__ Wq, const float* __restrict__ Wk, const float* __restrict__ Wv,
    const float* __restrict__ Wqp, const float* __restrict__ Wkp, const float* __restrict__ Wvp,
    float* __restrict__ q, float* __restrict__ k, float* __restrict__ vT,
    float* __restrict__ lqp, float* __restrict__ lkp, float* __restrict__ lvpT)
{
  int s0 = blockIdx.x*2;
  __shared__ float srs[2][CS];
  __shared__ float Rs[2][9];
  __shared__ float ts[2][3];
  for (int x = threadIdx.x; x < 2*CS; x += 256) ((float*)srs)[x] = sr[(size_t)s0*CS + x];
  if (threadIdx.x < 18) ((float*)Rs)[threadIdx.x] = rot[(size_t)s0*9 + threadIdx.x];
  if (threadIdx.x >= 64 && threadIdx.x < 70) ((float*)ts)[threadIdx.x-64] = trans[(size_t)s0*3 + threadIdx.x-64];
  __syncthreads();

  for (int task = threadIdx.x; task < 768; task += 256){
    if (task < 576){
      int which = task / 192;
      int he = task - which*192;
      int h = he >> 4, e = he & 15;
      const float* W = (which==0 ? Wq : (which==1 ? Wk : Wv)) + (size_t)he*CS;
      const float4* W4 = (const float4*)W;
      float acc[2] = {0.f,0.f};
      for (int cc = 0; cc < CS/4; ++cc){
        float4 w = W4[cc];
        #pragma unroll
        for (int r = 0; r < 2; ++r){
          const float* sp = srs[r] + cc*4;
          acc[r] += w.x*sp[0] + w.y*sp[1] + w.z*sp[2] + w.w*sp[3];
        }
      }
      #pragma unroll
      for (int r = 0; r < 2; ++r){
        int s = s0 + r;
        if (which == 0)      q[((size_t)h*S + s)*E + e] = acc[r];
        else if (which == 1) k[((size_t)h*S + s)*E + e] = acc[r];
        else                 vT[((size_t)h*E + e)*S + s] = acc[r];
      }
    } else {
      int pt = task - 576;
      int h = pt >> 4, slot = pt & 15;
      int kind, p; const float* W;
      if (slot < 4)      { kind = 0; p = slot;     W = Wqp + (size_t)((h*PQ+p)*3)*CS; }
      else if (slot < 8) { kind = 1; p = slot - 4; W = Wkp + (size_t)((h*PQ+p)*3)*CS; }
      else               { kind = 2; p = slot - 8; W = Wvp + (size_t)((h*PV+p)*3)*CS; }
      const float4* W0 = (const float4*)W;
      const float4* W1 = (const float4*)(W + CS);
      const float4* W2 = (const float4*)(W + 2*CS);
      float a0[2] = {0,0}, a1[2] = {0,0}, a2[2] = {0,0};
      for (int cc = 0; cc < CS/4; ++cc){
        float4 w0 = W0[cc], w1 = W1[cc], w2 = W2[cc];
        #pragma unroll
        for (int r = 0; r < 2; ++r){
          const float* sp = srs[r] + cc*4;
          a0[r] += w0.x*sp[0] + w0.y*sp[1] + w0.z*sp[2] + w0.w*sp[3];
          a1[r] += w1.x*sp[0] + w1.y*sp[1] + w1.z*sp[2] + w1.w*sp[3];
          a2[r] += w2.x*sp[0] + w2.y*sp[1] + w2.z*sp[2] + w2.w*sp[3];
        }
      }
      #pragma unroll
      for (int r = 0; r < 2; ++r){
        int s = s0 + r;
        float l0 = Rs[r][0]*a0[r] + Rs[r][1]*a1[r] + Rs[r][2]*a2[r] + ts[r][0];
        float l1 = Rs[r][3]*a0[r] + Rs[r][4]*a1[r] + Rs[r][5]*a2[r] + ts[r][1];
        float l2 = Rs[r][6]*a0[r] + Rs[r][7]*a1[r] + Rs[r][8]*a2[r] + ts[r][2];
        if (kind == 0){ float* d = lqp + ((size_t)h*S + s)*12 + p*3; d[0]=l0; d[1]=l1; d[2]=l2; }
        else if (kind == 1){ float* d = lkp + ((size_t)h*S + s)*12 + p*3; d[0]=l0; d[1]=l1; d[2]=l2; }
        else {
          float* dst = lvpT + (size_t)h*24*S;
          dst[(size_t)(p*3+0)*S + s] = l0;
          dst[(size_t)(p*3+1)*S + s] = l1;
          dst[(size_t)(p*3+2)*S + s] = l2;
        }
      }
    }
  }
}

// ---------------- kernel 1b: w_pair[h][r] = sum_c Wb[h][c]*pair[r][c] -----------
__global__ __launch_bounds__(256) void k_wpair(
    const float* __restrict__ pair, const float* __restrict__ Wb, float* __restrict__ wp)
{
  int r = blockIdx.x*256 + threadIdx.x;   // row in [0, S*S)
  const float4* prow = (const float4*)(pair + (size_t)r*CP);
  float acc[H];
  #pragma unroll
  for (int h = 0; h < H; ++h) acc[h] = 0.f;
  #pragma unroll
  for (int half = 0; half < 2; ++half){
    float4 buf[16];
    #pragma unroll
    for (int cc = 0; cc < 16; ++cc) buf[cc] = prow[half*16 + cc];
    #pragma unroll
    for (int h = 0; h < H; ++h){
      const float4* wb = (const float4*)(Wb + h*CP + half*64);  // uniform -> s_load
      float p0=0.f, p1=0.f, p2=0.f, p3=0.f;
      #pragma unroll
      for (int cc = 0; cc < 16; ++cc){
        float4 wv = wb[cc];
        p0 += wv.x*buf[cc].x; p1 += wv.y*buf[cc].y;
        p2 += wv.z*buf[cc].z; p3 += wv.w*buf[cc].w;
      }
      acc[h] += (p0+p1)+(p2+p3);
    }
  }
  #pragma unroll
  for (int h = 0; h < H; ++h) wp[(size_t)h*S*S + r] = acc[h];   // coalesced per h
}

// ---------------- kernel 2: logits (wp + single + frame) + softmax --------------
__global__ __launch_bounds__(256) void k_attn(
    const float* __restrict__ wp,
    const float* __restrict__ q, const float* __restrict__ k,
    const float* __restrict__ lqp, const float* __restrict__ lkp,
    const float* __restrict__ gamma, bf16* __restrict__ ab)
{
  int i    = blockIdx.x / 3;
  int hg   = blockIdx.x % 3;
  int lane = threadIdx.x & 63;
  int w    = __builtin_amdgcn_readfirstlane(threadIdx.x >> 6);  // wave id, uniform
  int h    = hg*4 + w;

  __shared__ float lgs[4][S];   // 12 KB

  const float* qrow = q   + ((size_t)h*S + i)*E;   // wave-uniform -> s_load
  const float* lqr  = lqp + ((size_t)h*S + i)*12;  // wave-uniform -> s_load
  const float* wrow = wp  + ((size_t)h*S + i)*S;
  float sf = -0.11785113019775793f * log1pf(__expf(gamma[h]));

  float qv[E];
  #pragma unroll
  for (int e = 0; e < E; ++e) qv[e] = qrow[e];
  float lq[12];
  #pragma unroll
  for (int x = 0; x < 12; ++x) lq[x] = lqr[x];

  float mloc = -1e30f;
  #pragma unroll 3
  for (int jj = 0; jj < 12; ++jj){
    int j = lane + jj*64;
    const float4* kr4 = (const float4*)(k   + ((size_t)h*S + j)*E);
    const float4* lk4 = (const float4*)(lkp + ((size_t)h*S + j)*12);
    float4 k0 = kr4[0], k1 = kr4[1], k2 = kr4[2], k3 = kr4[3];
    float4 p0 = lk4[0], p1 = lk4[1], p2 = lk4[2];
    float d = qv[0]*k0.x + qv[1]*k0.y + qv[2]*k0.z + qv[3]*k0.w
            + qv[4]*k1.x + qv[5]*k1.y + qv[6]*k1.z + qv[7]*k1.w
            + qv[8]*k2.x + qv[9]*k2.y + qv[10]*k2.z + qv[11]*k2.w
            + qv[12]*k3.x + qv[13]*k3.y + qv[14]*k3.z + qv[15]*k3.w;
    float d0 = lq[0]-p0.x, d1 = lq[1]-p0.y, d2  = lq[2]-p0.z,  d3  = lq[3]-p0.w;
    float d4 = lq[4]-p1.x, d5 = lq[5]-p1.y, d6  = lq[6]-p1.z,  d7  = lq[7]-p1.w;
    float d8 = lq[8]-p2.x, d9 = lq[9]-p2.y, d10 = lq[10]-p2.z, d11 = lq[11]-p2.w;
    float fr = d0*d0 + d1*d1 + d2*d2 + d3*d3 + d4*d4 + d5*d5
             + d6*d6 + d7*d7 + d8*d8 + d9*d9 + d10*d10 + d11*d11;
    float lg = wrow[j] + 0.25f*d + sf*fr;
    lgs[w][j] = lg;
    mloc = fmaxf(mloc, lg);
  }
  #pragma unroll
  for (int mk = 1; mk < 64; mk <<= 1) mloc = fmaxf(mloc, __shfl_xor(mloc, mk));

  float sum = 0.f;
  #pragma unroll 3
  for (int jj = 0; jj < 12; ++jj){
    int j = lane + jj*64;
    float v = __expf(lgs[w][j] - mloc);
    lgs[w][j] = v;
    sum += v;
  }
  #pragma unroll
  for (int mk = 1; mk < 64; mk <<= 1) sum += __shfl_xor(sum, mk);
  float inv = 1.f/sum;

  size_t base = ((size_t)h*S + i)*S;
  #pragma unroll 3
  for (int jj = 0; jj < 12; ++jj){
    int j = lane + jj*64;
    ab[base + j] = f2b(lgs[w][j]*inv);
  }
}

// ---------------- kernel 3: a_sum over queries -> asumT[j*H+h] (fp32, atomic) ----
__global__ __launch_bounds__(256) void k_asum(const bf16* __restrict__ ab, float* __restrict__ asumT)
{
  int h  = blockIdx.x;
  int i0 = blockIdx.y * 24;
  int t  = threadIdx.x;
  float a0 = 0.f, a1 = 0.f, a2 = 0.f;
  for (int i = i0; i < i0 + 24; ++i){
    const bf16* row = ab + ((size_t)h*S + i)*S;
    a0 += b2f(row[t]);
    a1 += b2f(row[t + 256]);
    a2 += b2f(row[t + 512]);
  }
  atomicAdd(&asumT[(t      )*H + h], a0);
  atomicAdd(&asumT[(t + 256)*H + h], a1);
  atomicAdd(&asumT[(t + 512)*H + h], a2);
}

// ---------------- kernel 4: o_single + o_local -> o_global + norms --------------
__global__ __launch_bounds__(256) void k_out_sv(
    const bf16* __restrict__ ab, const float* __restrict__ vT, const float* __restrict__ lvpT,
    const float* __restrict__ rot, const float* __restrict__ trans, bf16* __restrict__ attnb)
{
  int h    = blockIdx.x / (S/4);
  int i0   = (blockIdx.x % (S/4))*4;
  int w    = threadIdx.x >> 6;
  int lane = threadIdx.x & 63;
  int i = i0 + w;
  const uint4* ar4 = (const uint4*)(ab + ((size_t)h*S + i)*S);  // 96 uint4 per row
  float acc = 0.f;
  const float* src = nullptr;
  if (lane < 16)      src = vT   + ((size_t)h*E  + lane)*S;
  else if (lane < 40) src = lvpT + ((size_t)h*24 + (lane-16))*S;
  if (src){
    for (int jb = 0; jb < S/8; ++jb){
      float af[8]; up8(ar4[jb], af);
      float4 s0 = *(const float4*)(src + jb*8);
      float4 s1 = *(const float4*)(src + jb*8 + 4);
      acc += af[0]*s0.x + af[1]*s0.y + af[2]*s0.z + af[3]*s0.w
           + af[4]*s1.x + af[5]*s1.y + af[6]*s1.z + af[7]*s1.w;
    }
  }
  __shared__ float ol[4][24];
  __shared__ float ogs[4][24];
  int pd = lane - 16;
  if (lane >= 16 && lane < 40) ol[w][pd] = acc;
  __syncthreads();
  if (lane < 16){
    attnb[(size_t)i*FDIM + h*E + lane] = f2b(acc);
  } else if (lane < 40){
    int p = pd/3, d = pd%3;
    float r0 = rot[(size_t)i*9 + 0 + d];
    float r1 = rot[(size_t)i*9 + 3 + d];
    float r2 = rot[(size_t)i*9 + 6 + d];
    float x0 = ol[w][p*3+0] - trans[i*3+0];
    float x1 = ol[w][p*3+1] - trans[i*3+1];
    float x2 = ol[w][p*3+2] - trans[i*3+2];
    float og = r0*x0 + r1*x1 + r2*x2;
    attnb[(size_t)i*FDIM + OFF_PTS + p*(H*3) + h*3 + d] = f2b(og);
    ogs[w][pd] = og;
  }
  __syncthreads();
  if (lane >= 16 && lane < 40 && (pd % 3) == 0){
    int p = pd/3;
    float g0 = ogs[w][p*3], g1 = ogs[w][p*3+1], g2 = ogs[w][p*3+2];
    attnb[(size_t)i*FDIM + OFF_NORM + p*H + h] = f2b(sqrtf(g0*g0 + g1*g1 + g2*g2));
  }
}

// ---------------- kernel 5: o_pair[i,h,c] = sum_k asum[h,k]*pair[i,k,c] ---------
__global__ __launch_bounds__(512) void k_opair(const float* __restrict__ pair,
                                               const float* __restrict__ asumT,
                                               bf16* __restrict__ attnb)
{
  int i  = blockIdx.x;
  int t  = threadIdx.x;
  int c2 = t & 63;
  int g  = __builtin_amdgcn_readfirstlane(t >> 6);   // wave id 0..7, uniform
  float accx[H], accy[H];
  #pragma unroll
  for (int h = 0; h < H; ++h){ accx[h] = 0.f; accy[h] = 0.f; }
  const float2* prow = (const float2*)(pair + (size_t)i*S*CP) + c2;
  for (int kk = 0; kk < 96; ++kk){
    int kj = g*96 + kk;
    float2 pv = prow[(size_t)kj*64];
    const float* ap = asumT + kj*H;    // uniform -> s_load
    #pragma unroll
    for (int h = 0; h < H; ++h){
      accx[h] += ap[h]*pv.x;
      accy[h] += ap[h]*pv.y;
    }
  }
  __shared__ float part[8][H][CP];   // 48 KB
  #pragma unroll
  for (int h = 0; h < H; ++h)
    ((float2*)part[g][h])[c2] = make_float2(accx[h], accy[h]);
  __syncthreads();
  if (t < CP){
    #pragma unroll
    for (int h = 0; h < H; ++h){
      float s = part[0][h][t] + part[1][h][t] + part[2][h][t] + part[3][h][t]
              + part[4][h][t] + part[5][h][t] + part[6][h][t] + part[7][h][t];
      attnb[(size_t)i*FDIM + OFF_PAIR + h*CP + t] = f2b(s);
    }
  }
}

// ---------------- kernel 6: out += attn @ Wo^T (+bo), split-K x4 ---------------
// Was 192 blocks = 1152 waves (1.1/SIMD) -> latency-bound on the 528-iter serial
// L2 load loop. Now grid (192,4): chunk ck covers 132 float4 of the dot; fp32
// atomicAdd into out (zeroed by memset); bias added by chunk 0. 4608 waves.
__global__ __launch_bounds__(384) void k_final(const bf16* __restrict__ attnb,
                                               const float* __restrict__ Wo,
                                               const float* __restrict__ bo,
                                               float* __restrict__ out)
{
  int i0 = blockIdx.x*4;
  int ck = blockIdx.y;                     // 0..3
  int o  = threadIdx.x;
  const float4* wrow = (const float4*)(Wo + (size_t)o*FDIM) + ck*132;
  const unsigned* a0 = (const unsigned*)(attnb + (size_t)i0*FDIM) + ck*264;  // uniform
  const unsigned* a1 = a0 + FDIM/2;
  const unsigned* a2 = a1 + FDIM/2;
  const unsigned* a3 = a2 + FDIM/2;
  float c0=0.f, c1=0.f, c2=0.f, c3=0.f;
  for (int cc = 0; cc < 132; ++cc){
    float4 wv = wrow[cc];
    unsigned u;
    u = a0[cc*2]; c0 += wv.x*blo(u)+wv.y*bhi(u); u = a0[cc*2+1]; c0 += wv.z*blo(u)+wv.w*bhi(u);
    u = a1[cc*2]; c1 += wv.x*blo(u)+wv.y*bhi(u); u = a1[cc*2+1]; c1 += wv.z*blo(u)+wv.w*bhi(u);
    u = a2[cc*2]; c2 += wv.x*blo(u)+wv.y*bhi(u); u = a2[cc*2+1]; c2 += wv.z*blo(u)+wv.w*bhi(u);
    u = a3[cc*2]; c3 += wv.x*blo(u)+wv.y*bhi(u); u = a3[cc*2+1]; c3 += wv.z*blo(u)+wv.w*bhi(u);
  }
  if (ck == 0){
    float b = bo[o];
    c0 += b; c1 += b; c2 += b; c3 += b;
  }
  atomicAdd(&out[(size_t)(i0+0)*CS + o], c0);
  atomicAdd(&out[(size_t)(i0+1)*CS + o], c1);
  atomicAdd(&out[(size_t)(i0+2)*CS + o], c2);
  atomicAdd(&out[(size_t)(i0+3)*CS + o], c3);
}

extern "C" void kernel_launch(void* const* d_in, const int* in_sizes, int n_in,
                              void* d_out, int out_size, void* d_ws, size_t ws_size,
                              hipStream_t stream)
{
  const float* sr    = (const float*)d_in[0];
  const float* pair  = (const float*)d_in[1];
  const float* rot   = (const float*)d_in[2];
  const float* trans = (const float*)d_in[3];
  const float* Wq    = (const float*)d_in[4];
  const float* Wk    = (const float*)d_in[5];
  const float* Wv    = (const float*)d_in[6];
  const float* Wqp   = (const float*)d_in[7];
  const float* Wkp   = (const float*)d_in[8];
  const float* Wvp   = (const float*)d_in[9];
  const float* Wb    = (const float*)d_in[10];
  const float* Wo    = (const float*)d_in[11];
  const float* bo    = (const float*)d_in[12];
  const float* gamma = (const float*)d_in[13];

  // workspace layout (float units); total ~12.32M floats = 49.3 MB
  float* ws    = (float*)d_ws;
  float* q     = ws;                  // 147456
  float* k     = q     + 147456;      // 147456
  float* vT    = k     + 147456;      // 147456 [h][e][s]
  float* lqp   = vT    + 147456;      // 110592
  float* lkp   = lqp   + 110592;      // 110592
  float* lvpT  = lkp   + 110592;      // 221184 [h][pd][s]
  float* asumT = lvpT  + 221184;      // 9216  [j][h]
  bf16*  ab    = (bf16*)(asumT + 9216);              // H*S*S bf16
  bf16*  attnb = (bf16*)(asumT + 9216 + 3538944);    // S*FDIM bf16
  float* wp    = asumT + 9216 + 3538944 + 811008;    // H*S*S fp32 logits
  float* out = (float*)d_out;

  hipMemsetAsync(asumT, 0, (size_t)S*H*sizeof(float), stream);
  hipMemsetAsync(out,   0, (size_t)S*CS*sizeof(float), stream);
  k_proj  <<<S/2,          256, 0, stream>>>(sr, rot, trans, Wq, Wk, Wv, Wqp, Wkp, Wvp,
                                             q, k, vT, lqp, lkp, lvpT);
  k_wpair <<<(S*S)/256,    256, 0, stream>>>(pair, Wb, wp);
  k_attn  <<<S*3,          256, 0, stream>>>(wp, q, k, lqp, lkp, gamma, ab);
  k_asum  <<<dim3(H, 32),  256, 0, stream>>>(ab, asumT);
  k_out_sv<<<H*(S/4),      256, 0, stream>>>(ab, vT, lvpT, rot, trans, attnb);
  k_opair <<<S,            512, 0, stream>>>(pair, asumT, attnb);
  k_final <<<dim3(S/4, 4), 384, 0, stream>>>(attnb, Wo, bo, out);
}

// Round 4
// 880.033 us; speedup vs baseline: 1.3215x; 1.0354x over previous
//
#include <hip/hip_runtime.h>
#include <hip/hip_bf16.h>

#define S 768
#define CS 384
#define CP 128
#define E 16
#define PQ 4
#define PV 8
#define H 12
#define FDIM 2112          // H*(CP+E+PV*4)
#define OFF_PAIR 192       // H*E
#define OFF_PTS 1728       // +H*CP
#define OFF_NORM 2016      // +PV*H*3

typedef __hip_bfloat16 bf16;

__device__ __forceinline__ float b2f(bf16 x){ return __bfloat162float(x); }
__device__ __forceinline__ bf16 f2b(float x){ return __float2bfloat16(x); }
__device__ __forceinline__ float blo(unsigned u){ return __uint_as_float(u << 16); }
__device__ __forceinline__ float bhi(unsigned u){ return __uint_as_float(u & 0xffff0000u); }
__device__ __forceinline__ void up8(uint4 u, float* f){
  f[0]=blo(u.x); f[1]=bhi(u.x); f[2]=blo(u.y); f[3]=bhi(u.y);
  f[4]=blo(u.z); f[5]=bhi(u.z); f[6]=blo(u.w); f[7]=bhi(u.w);
}

// ---------------- fused kernel A: k_proj (blocks 0..383) + k_wpair (384..2687) --
// proj and wpair are data-independent; fusing them into one dispatch lets proj's
// L2-bound W-streaming hide under wpair's HBM pair-stream. Short job first.
__global__ __launch_bounds__(256) void k_proj_wpair(
    const float* __restrict__ sr, const float* __restrict__ rot, const float* __restrict__ trans,
    const float* __restrict__ Wq, const float* __restrict__ Wk, const float* __restrict__ Wv,
    const float* __restrict__ Wqp, const float* __restrict__ Wkp, const float* __restrict__ Wvp,
    float* __restrict__ q, float* __restrict__ k, float* __restrict__ vT,
    float* __restrict__ lqp, float* __restrict__ lkp, float* __restrict__ lvpT,
    const float* __restrict__ pair, const float* __restrict__ Wb, float* __restrict__ wp)
{
  if (blockIdx.x < S/2){
    // ---- k_proj body: 2 residues/block ----
    int s0 = blockIdx.x*2;
    __shared__ float srs[2][CS];
    __shared__ float Rs[2][9];
    __shared__ float ts[2][3];
    for (int x = threadIdx.x; x < 2*CS; x += 256) ((float*)srs)[x] = sr[(size_t)s0*CS + x];
    if (threadIdx.x < 18) ((float*)Rs)[threadIdx.x] = rot[(size_t)s0*9 + threadIdx.x];
    if (threadIdx.x >= 64 && threadIdx.x < 70) ((float*)ts)[threadIdx.x-64] = trans[(size_t)s0*3 + threadIdx.x-64];
    __syncthreads();

    for (int task = threadIdx.x; task < 768; task += 256){
      if (task < 576){
        int which = task / 192;
        int he = task - which*192;
        int h = he >> 4, e = he & 15;
        const float* W = (which==0 ? Wq : (which==1 ? Wk : Wv)) + (size_t)he*CS;
        const float4* W4 = (const float4*)W;
        float acc[2] = {0.f,0.f};
        for (int cc = 0; cc < CS/4; ++cc){
          float4 w = W4[cc];
          #pragma unroll
          for (int r = 0; r < 2; ++r){
            const float* sp = srs[r] + cc*4;
            acc[r] += w.x*sp[0] + w.y*sp[1] + w.z*sp[2] + w.w*sp[3];
          }
        }
        #pragma unroll
        for (int r = 0; r < 2; ++r){
          int s = s0 + r;
          if (which == 0)      q[((size_t)h*S + s)*E + e] = acc[r];
          else if (which == 1) k[((size_t)h*S + s)*E + e] = acc[r];
          else                 vT[((size_t)h*E + e)*S + s] = acc[r];
        }
      } else {
        int pt = task - 576;
        int h = pt >> 4, slot = pt & 15;
        int kind, p; const float* W;
        if (slot < 4)      { kind = 0; p = slot;     W = Wqp + (size_t)((h*PQ+p)*3)*CS; }
        else if (slot < 8) { kind = 1; p = slot - 4; W = Wkp + (size_t)((h*PQ+p)*3)*CS; }
        else               { kind = 2; p = slot - 8; W = Wvp + (size_t)((h*PV+p)*3)*CS; }
        const float4* W0 = (const float4*)W;
        const float4* W1 = (const float4*)(W + CS);
        const float4* W2 = (const float4*)(W + 2*CS);
        float a0[2] = {0,0}, a1[2] = {0,0}, a2[2] = {0,0};
        for (int cc = 0; cc < CS/4; ++cc){
          float4 w0 = W0[cc], w1 = W1[cc], w2 = W2[cc];
          #pragma unroll
          for (int r = 0; r < 2; ++r){
            const float* sp = srs[r] + cc*4;
            a0[r] += w0.x*sp[0] + w0.y*sp[1] + w0.z*sp[2] + w0.w*sp[3];
            a1[r] += w1.x*sp[0] + w1.y*sp[1] + w1.z*sp[2] + w1.w*sp[3];
            a2[r] += w2.x*sp[0] + w2.y*sp[1] + w2.z*sp[2] + w2.w*sp[3];
          }
        }
        #pragma unroll
        for (int r = 0; r < 2; ++r){
          int s = s0 + r;
          float l0 = Rs[r][0]*a0[r] + Rs[r][1]*a1[r] + Rs[r][2]*a2[r] + ts[r][0];
          float l1 = Rs[r][3]*a0[r] + Rs[r][4]*a1[r] + Rs[r][5]*a2[r] + ts[r][1];
          float l2 = Rs[r][6]*a0[r] + Rs[r][7]*a1[r] + Rs[r][8]*a2[r] + ts[r][2];
          if (kind == 0){ float* d = lqp + ((size_t)h*S + s)*12 + p*3; d[0]=l0; d[1]=l1; d[2]=l2; }
          else if (kind == 1){ float* d = lkp + ((size_t)h*S + s)*12 + p*3; d[0]=l0; d[1]=l1; d[2]=l2; }
          else {
            float* dst = lvpT + (size_t)h*24*S;
            dst[(size_t)(p*3+0)*S + s] = l0;
            dst[(size_t)(p*3+1)*S + s] = l1;
            dst[(size_t)(p*3+2)*S + s] = l2;
          }
        }
      }
    }
  } else {
    // ---- k_wpair body: one pair row (512 B) per thread ----
    int r = (blockIdx.x - S/2)*256 + threadIdx.x;   // row in [0, S*S)
    const float4* prow = (const float4*)(pair + (size_t)r*CP);
    float acc[H];
    #pragma unroll
    for (int h = 0; h < H; ++h) acc[h] = 0.f;
    #pragma unroll
    for (int half = 0; half < 2; ++half){
      float4 buf[16];
      #pragma unroll
      for (int cc = 0; cc < 16; ++cc) buf[cc] = prow[half*16 + cc];
      #pragma unroll
      for (int h = 0; h < H; ++h){
        const float4* wb = (const float4*)(Wb + h*CP + half*64);  // uniform -> s_load
        float p0=0.f, p1=0.f, p2=0.f, p3=0.f;
        #pragma unroll
        for (int cc = 0; cc < 16; ++cc){
          float4 wv = wb[cc];
          p0 += wv.x*buf[cc].x; p1 += wv.y*buf[cc].y;
          p2 += wv.z*buf[cc].z; p3 += wv.w*buf[cc].w;
        }
        acc[h] += (p0+p1)+(p2+p3);
      }
    }
    #pragma unroll
    for (int h = 0; h < H; ++h) wp[(size_t)h*S*S + r] = acc[h];   // coalesced per h
  }
}

// ---------------- kernel 2: logits (wp + single + frame) + softmax --------------
__global__ __launch_bounds__(256) void k_attn(
    const float* __restrict__ wp,
    const float* __restrict__ q, const float* __restrict__ k,
    const float* __restrict__ lqp, const float* __restrict__ lkp,
    const float* __restrict__ gamma, bf16* __restrict__ ab)
{
  int i    = blockIdx.x / 3;
  int hg   = blockIdx.x % 3;
  int lane = threadIdx.x & 63;
  int w    = __builtin_amdgcn_readfirstlane(threadIdx.x >> 6);  // wave id, uniform
  int h    = hg*4 + w;

  __shared__ float lgs[4][S];   // 12 KB

  const float* qrow = q   + ((size_t)h*S + i)*E;   // wave-uniform -> s_load
  const float* lqr  = lqp + ((size_t)h*S + i)*12;  // wave-uniform -> s_load
  const float* wrow = wp  + ((size_t)h*S + i)*S;
  float sf = -0.11785113019775793f * log1pf(__expf(gamma[h]));

  float qv[E];
  #pragma unroll
  for (int e = 0; e < E; ++e) qv[e] = qrow[e];
  float lq[12];
  #pragma unroll
  for (int x = 0; x < 12; ++x) lq[x] = lqr[x];

  float mloc = -1e30f;
  #pragma unroll 3
  for (int jj = 0; jj < 12; ++jj){
    int j = lane + jj*64;
    const float4* kr4 = (const float4*)(k   + ((size_t)h*S + j)*E);
    const float4* lk4 = (const float4*)(lkp + ((size_t)h*S + j)*12);
    float4 k0 = kr4[0], k1 = kr4[1], k2 = kr4[2], k3 = kr4[3];
    float4 p0 = lk4[0], p1 = lk4[1], p2 = lk4[2];
    float d = qv[0]*k0.x + qv[1]*k0.y + qv[2]*k0.z + qv[3]*k0.w
            + qv[4]*k1.x + qv[5]*k1.y + qv[6]*k1.z + qv[7]*k1.w
            + qv[8]*k2.x + qv[9]*k2.y + qv[10]*k2.z + qv[11]*k2.w
            + qv[12]*k3.x + qv[13]*k3.y + qv[14]*k3.z + qv[15]*k3.w;
    float d0 = lq[0]-p0.x, d1 = lq[1]-p0.y, d2  = lq[2]-p0.z,  d3  = lq[3]-p0.w;
    float d4 = lq[4]-p1.x, d5 = lq[5]-p1.y, d6  = lq[6]-p1.z,  d7  = lq[7]-p1.w;
    float d8 = lq[8]-p2.x, d9 = lq[9]-p2.y, d10 = lq[10]-p2.z, d11 = lq[11]-p2.w;
    float fr = d0*d0 + d1*d1 + d2*d2 + d3*d3 + d4*d4 + d5*d5
             + d6*d6 + d7*d7 + d8*d8 + d9*d9 + d10*d10 + d11*d11;
    float lg = wrow[j] + 0.25f*d + sf*fr;
    lgs[w][j] = lg;
    mloc = fmaxf(mloc, lg);
  }
  #pragma unroll
  for (int mk = 1; mk < 64; mk <<= 1) mloc = fmaxf(mloc, __shfl_xor(mloc, mk));

  float sum = 0.f;
  #pragma unroll 3
  for (int jj = 0; jj < 12; ++jj){
    int j = lane + jj*64;
    float v = __expf(lgs[w][j] - mloc);
    lgs[w][j] = v;
    sum += v;
  }
  #pragma unroll
  for (int mk = 1; mk < 64; mk <<= 1) sum += __shfl_xor(sum, mk);
  float inv = 1.f/sum;

  size_t base = ((size_t)h*S + i)*S;
  #pragma unroll 3
  for (int jj = 0; jj < 12; ++jj){
    int j = lane + jj*64;
    ab[base + j] = f2b(lgs[w][j]*inv);
  }
}

// ---------------- fused kernel B: k_asum (blocks 0..383) + k_out_sv (384..2687) -
// Both consume only ab and write disjoint outputs; asum's small reduction hides
// under out_sv's streaming. Short job first.
__global__ __launch_bounds__(256) void k_sv_asum(
    const bf16* __restrict__ ab, const float* __restrict__ vT, const float* __restrict__ lvpT,
    const float* __restrict__ rot, const float* __restrict__ trans,
    bf16* __restrict__ attnb, float* __restrict__ asumT)
{
  if (blockIdx.x < 384){
    // ---- k_asum body ----
    int h  = blockIdx.x / 32;
    int i0 = (blockIdx.x % 32) * 24;
    int t  = threadIdx.x;
    float a0 = 0.f, a1 = 0.f, a2 = 0.f;
    for (int i = i0; i < i0 + 24; ++i){
      const bf16* row = ab + ((size_t)h*S + i)*S;
      a0 += b2f(row[t]);
      a1 += b2f(row[t + 256]);
      a2 += b2f(row[t + 512]);
    }
    atomicAdd(&asumT[(t      )*H + h], a0);
    atomicAdd(&asumT[(t + 256)*H + h], a1);
    atomicAdd(&asumT[(t + 512)*H + h], a2);
  } else {
    // ---- k_out_sv body ----
    int bid  = blockIdx.x - 384;
    int h    = bid / (S/4);
    int i0   = (bid % (S/4))*4;
    int w    = threadIdx.x >> 6;
    int lane = threadIdx.x & 63;
    int i = i0 + w;
    const uint4* ar4 = (const uint4*)(ab + ((size_t)h*S + i)*S);  // 96 uint4 per row
    float acc = 0.f;
    const float* src = nullptr;
    if (lane < 16)      src = vT   + ((size_t)h*E  + lane)*S;
    else if (lane < 40) src = lvpT + ((size_t)h*24 + (lane-16))*S;
    if (src){
      for (int jb = 0; jb < S/8; ++jb){
        float af[8]; up8(ar4[jb], af);
        float4 s0 = *(const float4*)(src + jb*8);
        float4 s1 = *(const float4*)(src + jb*8 + 4);
        acc += af[0]*s0.x + af[1]*s0.y + af[2]*s0.z + af[3]*s0.w
             + af[4]*s1.x + af[5]*s1.y + af[6]*s1.z + af[7]*s1.w;
      }
    }
    __shared__ float ol[4][24];
    __shared__ float ogs[4][24];
    int pd = lane - 16;
    if (lane >= 16 && lane < 40) ol[w][pd] = acc;
    __syncthreads();
    if (lane < 16){
      attnb[(size_t)i*FDIM + h*E + lane] = f2b(acc);
    } else if (lane < 40){
      int p = pd/3, d = pd%3;
      float r0 = rot[(size_t)i*9 + 0 + d];
      float r1 = rot[(size_t)i*9 + 3 + d];
      float r2 = rot[(size_t)i*9 + 6 + d];
      float x0 = ol[w][p*3+0] - trans[i*3+0];
      float x1 = ol[w][p*3+1] - trans[i*3+1];
      float x2 = ol[w][p*3+2] - trans[i*3+2];
      float og = r0*x0 + r1*x1 + r2*x2;
      attnb[(size_t)i*FDIM + OFF_PTS + p*(H*3) + h*3 + d] = f2b(og);
      ogs[w][pd] = og;
    }
    __syncthreads();
    if (lane >= 16 && lane < 40 && (pd % 3) == 0){
      int p = pd/3;
      float g0 = ogs[w][p*3], g1 = ogs[w][p*3+1], g2 = ogs[w][p*3+2];
      attnb[(size_t)i*FDIM + OFF_NORM + p*H + h] = f2b(sqrtf(g0*g0 + g1*g1 + g2*g2));
    }
  }
}

// ---------------- kernel 5: o_pair[i,h,c] = sum_k asum[h,k]*pair[i,k,c] ---------
__global__ __launch_bounds__(512) void k_opair(const float* __restrict__ pair,
                                               const float* __restrict__ asumT,
                                               bf16* __restrict__ attnb)
{
  int i  = blockIdx.x;
  int t  = threadIdx.x;
  int c2 = t & 63;
  int g  = __builtin_amdgcn_readfirstlane(t >> 6);   // wave id 0..7, uniform
  float accx[H], accy[H];
  #pragma unroll
  for (int h = 0; h < H; ++h){ accx[h] = 0.f; accy[h] = 0.f; }
  const float2* prow = (const float2*)(pair + (size_t)i*S*CP) + c2;
  for (int kk = 0; kk < 96; ++kk){
    int kj = g*96 + kk;
    float2 pv = prow[(size_t)kj*64];
    const float* ap = asumT + kj*H;    // uniform -> s_load
    #pragma unroll
    for (int h = 0; h < H; ++h){
      accx[h] += ap[h]*pv.x;
      accy[h] += ap[h]*pv.y;
    }
  }
  __shared__ float part[8][H][CP];   // 48 KB
  #pragma unroll
  for (int h = 0; h < H; ++h)
    ((float2*)part[g][h])[c2] = make_float2(accx[h], accy[h]);
  __syncthreads();
  if (t < CP){
    #pragma unroll
    for (int h = 0; h < H; ++h){
      float s = part[0][h][t] + part[1][h][t] + part[2][h][t] + part[3][h][t]
              + part[4][h][t] + part[5][h][t] + part[6][h][t] + part[7][h][t];
      attnb[(size_t)i*FDIM + OFF_PAIR + h*CP + t] = f2b(s);
    }
  }
}

// ---------------- kernel 6: out += attn @ Wo^T (+bo), split-K x4 ---------------
__global__ __launch_bounds__(384) void k_final(const bf16* __restrict__ attnb,
                                               const float* __restrict__ Wo,
                                               const float* __restrict__ bo,
                                               float* __restrict__ out)
{
  int i0 = blockIdx.x*4;
  int ck = blockIdx.y;                     // 0..3
  int o  = threadIdx.x;
  const float4* wrow = (const float4*)(Wo + (size_t)o*FDIM) + ck*132;
  const unsigned* a0 = (const unsigned*)(attnb + (size_t)i0*FDIM) + ck*264;  // uniform
  const unsigned* a1 = a0 + FDIM/2;
  const unsigned* a2 = a1 + FDIM/2;
  const unsigned* a3 = a2 + FDIM/2;
  float c0=0.f, c1=0.f, c2=0.f, c3=0.f;
  for (int cc = 0; cc < 132; ++cc){
    float4 wv = wrow[cc];
    unsigned u;
    u = a0[cc*2]; c0 += wv.x*blo(u)+wv.y*bhi(u); u = a0[cc*2+1]; c0 += wv.z*blo(u)+wv.w*bhi(u);
    u = a1[cc*2]; c1 += wv.x*blo(u)+wv.y*bhi(u); u = a1[cc*2+1]; c1 += wv.z*blo(u)+wv.w*bhi(u);
    u = a2[cc*2]; c2 += wv.x*blo(u)+wv.y*bhi(u); u = a2[cc*2+1]; c2 += wv.z*blo(u)+wv.w*bhi(u);
    u = a3[cc*2]; c3 += wv.x*blo(u)+wv.y*bhi(u); u = a3[cc*2+1]; c3 += wv.z*blo(u)+wv.w*bhi(u);
  }
  if (ck == 0){
    float b = bo[o];
    c0 += b; c1 += b; c2 += b; c3 += b;
  }
  atomicAdd(&out[(size_t)(i0+0)*CS + o], c0);
  atomicAdd(&out[(size_t)(i0+1)*CS + o], c1);
  atomicAdd(&out[(size_t)(i0+2)*CS + o], c2);
  atomicAdd(&out[(size_t)(i0+3)*CS + o], c3);
}

extern "C" void kernel_launch(void* const* d_in, const int* in_sizes, int n_in,
                              void* d_out, int out_size, void* d_ws, size_t ws_size,
                              hipStream_t stream)
{
  const float* sr    = (const float*)d_in[0];
  const float* pair  = (const float*)d_in[1];
  const float* rot   = (const float*)d_in[2];
  const float* trans = (const float*)d_in[3];
  const float* Wq    = (const float*)d_in[4];
  const float* Wk    = (const float*)d_in[5];
  const float* Wv    = (const float*)d_in[6];
  const float* Wqp   = (const float*)d_in[7];
  const float* Wkp   = (const float*)d_in[8];
  const float* Wvp   = (const float*)d_in[9];
  const float* Wb    = (const float*)d_in[10];
  const float* Wo    = (const float*)d_in[11];
  const float* bo    = (const float*)d_in[12];
  const float* gamma = (const float*)d_in[13];

  // workspace layout (float units); total ~12.32M floats = 49.3 MB
  float* ws    = (float*)d_ws;
  float* q     = ws;                  // 147456
  float* k     = q     + 147456;      // 147456
  float* vT    = k     + 147456;      // 147456 [h][e][s]
  float* lqp   = vT    + 147456;      // 110592
  float* lkp   = lqp   + 110592;      // 110592
  float* lvpT  = lkp   + 110592;      // 221184 [h][pd][s]
  float* asumT = lvpT  + 221184;      // 9216  [j][h]
  bf16*  ab    = (bf16*)(asumT + 9216);              // H*S*S bf16
  bf16*  attnb = (bf16*)(asumT + 9216 + 3538944);    // S*FDIM bf16
  float* wp    = asumT + 9216 + 3538944 + 811008;    // H*S*S fp32 logits
  float* out = (float*)d_out;

  hipMemsetAsync(asumT, 0, (size_t)S*H*sizeof(float), stream);
  hipMemsetAsync(out,   0, (size_t)S*CS*sizeof(float), stream);
  k_proj_wpair<<<S/2 + (S*S)/256, 256, 0, stream>>>(sr, rot, trans, Wq, Wk, Wv, Wqp, Wkp, Wvp,
                                                    q, k, vT, lqp, lkp, lvpT, pair, Wb, wp);
  k_attn      <<<S*3,             256, 0, stream>>>(wp, q, k, lqp, lkp, gamma, ab);
  k_sv_asum   <<<384 + H*(S/4),   256, 0, stream>>>(ab, vT, lvpT, rot, trans, attnb, asumT);
  k_opair     <<<S,               512, 0, stream>>>(pair, asumT, attnb);
  k_final     <<<dim3(S/4, 4),    384, 0, stream>>>(attnb, Wo, bo, out);
}

// Round 5
// 750.834 us; speedup vs baseline: 1.5489x; 1.1721x over previous
//
#include <hip/hip_runtime.h>
#include <hip/hip_bf16.h>

#define S 768
#define CS 384
#define CP 128
#define E 16
#define PQ 4
#define PV 8
#define H 12
#define FDIM 2112          // H*(CP+E+PV*4)
#define OFF_PAIR 192       // H*E
#define OFF_PTS 1728       // +H*CP
#define OFF_NORM 2016      // +PV*H*3

typedef __hip_bfloat16 bf16;

__device__ __forceinline__ float b2f(bf16 x){ return __bfloat162float(x); }
__device__ __forceinline__ bf16 f2b(float x){ return __float2bfloat16(x); }
__device__ __forceinline__ float blo(unsigned u){ return __uint_as_float(u << 16); }
__device__ __forceinline__ float bhi(unsigned u){ return __uint_as_float(u & 0xffff0000u); }
__device__ __forceinline__ unsigned pk2(float a, float b){
  bf16 x = f2b(a), y = f2b(b);
  unsigned short ux = *reinterpret_cast<unsigned short*>(&x);
  unsigned short uy = *reinterpret_cast<unsigned short*>(&y);
  return (unsigned)ux | ((unsigned)uy << 16);
}

// ---------------- fused kernel A: k_proj (blocks 0..383) + k_wpair (384..2687) --
// proj writes: q/lqp row-major (wave-uniform consumers), kT/lkpT TRANSPOSED
// [h][e|x][s] (lane-j-contiguous consumers in k_attn), and V packed as bf16
// pairs vf2[h][jp][48] (lane-c-contiguous consumer in out_sv).
__global__ __launch_bounds__(256) void k_proj_wpair(
    const float* __restrict__ sr, const float* __restrict__ rot, const float* __restrict__ trans,
    const float* __restrict__ Wq, const float* __restrict__ Wk, const float* __restrict__ Wv,
    const float* __restrict__ Wqp, const float* __restrict__ Wkp, const float* __restrict__ Wvp,
    float* __restrict__ q, float* __restrict__ kT, unsigned* __restrict__ vf2,
    float* __restrict__ lqp, float* __restrict__ lkpT,
    const float* __restrict__ pair, const float* __restrict__ Wb, float* __restrict__ wp)
{
  if (blockIdx.x < S/2){
    // ---- k_proj body: 2 residues/block; jp = blockIdx.x ----
    int s0 = blockIdx.x*2;
    // zero the padding cols 40..47 of vf2 for this jp (all heads)
    if (threadIdx.x < 96){
      int hh = threadIdx.x >> 3, c = 40 + (threadIdx.x & 7);
      vf2[((size_t)hh*(S/2) + blockIdx.x)*48 + c] = 0u;
    }
    __shared__ float srs[2][CS];
    __shared__ float Rs[2][9];
    __shared__ float ts[2][3];
    for (int x = threadIdx.x; x < 2*CS; x += 256) ((float*)srs)[x] = sr[(size_t)s0*CS + x];
    if (threadIdx.x < 18) ((float*)Rs)[threadIdx.x] = rot[(size_t)s0*9 + threadIdx.x];
    if (threadIdx.x >= 64 && threadIdx.x < 70) ((float*)ts)[threadIdx.x-64] = trans[(size_t)s0*3 + threadIdx.x-64];
    __syncthreads();

    for (int task = threadIdx.x; task < 768; task += 256){
      if (task < 576){
        int which = task / 192;
        int he = task - which*192;
        int h = he >> 4, e = he & 15;
        const float* W = (which==0 ? Wq : (which==1 ? Wk : Wv)) + (size_t)he*CS;
        const float4* W4 = (const float4*)W;
        float acc[2] = {0.f,0.f};
        for (int cc = 0; cc < CS/4; ++cc){
          float4 w = W4[cc];
          #pragma unroll
          for (int r = 0; r < 2; ++r){
            const float* sp = srs[r] + cc*4;
            acc[r] += w.x*sp[0] + w.y*sp[1] + w.z*sp[2] + w.w*sp[3];
          }
        }
        if (which == 0){
          #pragma unroll
          for (int r = 0; r < 2; ++r) q[((size_t)h*S + s0+r)*E + e] = acc[r];
        } else if (which == 1){
          #pragma unroll
          for (int r = 0; r < 2; ++r) kT[((size_t)h*E + e)*S + s0+r] = acc[r];
        } else {
          vf2[((size_t)h*(S/2) + (s0>>1))*48 + e] = pk2(acc[0], acc[1]);
        }
      } else {
        int pt = task - 576;
        int h = pt >> 4, slot = pt & 15;
        int kind, p; const float* W;
        if (slot < 4)      { kind = 0; p = slot;     W = Wqp + (size_t)((h*PQ+p)*3)*CS; }
        else if (slot < 8) { kind = 1; p = slot - 4; W = Wkp + (size_t)((h*PQ+p)*3)*CS; }
        else               { kind = 2; p = slot - 8; W = Wvp + (size_t)((h*PV+p)*3)*CS; }
        const float4* W0 = (const float4*)W;
        const float4* W1 = (const float4*)(W + CS);
        const float4* W2 = (const float4*)(W + 2*CS);
        float a0[2] = {0,0}, a1[2] = {0,0}, a2[2] = {0,0};
        for (int cc = 0; cc < CS/4; ++cc){
          float4 w0 = W0[cc], w1 = W1[cc], w2 = W2[cc];
          #pragma unroll
          for (int r = 0; r < 2; ++r){
            const float* sp = srs[r] + cc*4;
            a0[r] += w0.x*sp[0] + w0.y*sp[1] + w0.z*sp[2] + w0.w*sp[3];
            a1[r] += w1.x*sp[0] + w1.y*sp[1] + w1.z*sp[2] + w1.w*sp[3];
            a2[r] += w2.x*sp[0] + w2.y*sp[1] + w2.z*sp[2] + w2.w*sp[3];
          }
        }
        float lv[2][3];
        #pragma unroll
        for (int r = 0; r < 2; ++r){
          int s = s0 + r;
          float l0 = Rs[r][0]*a0[r] + Rs[r][1]*a1[r] + Rs[r][2]*a2[r] + ts[r][0];
          float l1 = Rs[r][3]*a0[r] + Rs[r][4]*a1[r] + Rs[r][5]*a2[r] + ts[r][1];
          float l2 = Rs[r][6]*a0[r] + Rs[r][7]*a1[r] + Rs[r][8]*a2[r] + ts[r][2];
          if (kind == 0){ float* d = lqp + ((size_t)h*S + s)*12 + p*3; d[0]=l0; d[1]=l1; d[2]=l2; }
          else if (kind == 1){
            float* dst = lkpT + (size_t)h*12*S;
            dst[(size_t)(p*3+0)*S + s] = l0;
            dst[(size_t)(p*3+1)*S + s] = l1;
            dst[(size_t)(p*3+2)*S + s] = l2;
          } else {
            lv[r][0]=l0; lv[r][1]=l1; lv[r][2]=l2;
          }
        }
        if (kind == 2){
          size_t base = ((size_t)h*(S/2) + (s0>>1))*48 + 16 + p*3;
          vf2[base+0] = pk2(lv[0][0], lv[1][0]);
          vf2[base+1] = pk2(lv[0][1], lv[1][1]);
          vf2[base+2] = pk2(lv[0][2], lv[1][2]);
        }
      }
    }
  } else {
    // ---- k_wpair body: one pair row (512 B) per thread ----
    int r = (blockIdx.x - S/2)*256 + threadIdx.x;   // row in [0, S*S)
    const float4* prow = (const float4*)(pair + (size_t)r*CP);
    float acc[H];
    #pragma unroll
    for (int h = 0; h < H; ++h) acc[h] = 0.f;
    #pragma unroll
    for (int half = 0; half < 2; ++half){
      float4 buf[16];
      #pragma unroll
      for (int cc = 0; cc < 16; ++cc) buf[cc] = prow[half*16 + cc];
      #pragma unroll
      for (int h = 0; h < H; ++h){
        const float4* wb = (const float4*)(Wb + h*CP + half*64);  // uniform -> s_load
        float p0=0.f, p1=0.f, p2=0.f, p3=0.f;
        #pragma unroll
        for (int cc = 0; cc < 16; ++cc){
          float4 wv = wb[cc];
          p0 += wv.x*buf[cc].x; p1 += wv.y*buf[cc].y;
          p2 += wv.z*buf[cc].z; p3 += wv.w*buf[cc].w;
        }
        acc[h] += (p0+p1)+(p2+p3);
      }
    }
    #pragma unroll
    for (int h = 0; h < H; ++h) wp[(size_t)h*S*S + r] = acc[h];   // coalesced per h
  }
}

// ---------------- kernel 2: logits (wp + single + frame) + softmax --------------
// kT/lkpT are lane-j contiguous: each load instr spans 256 B (4 lines) instead of
// 64 distinct lines -> no L1 transaction storm.
__global__ __launch_bounds__(256) void k_attn(
    const float* __restrict__ wp,
    const float* __restrict__ q, const float* __restrict__ kT,
    const float* __restrict__ lqp, const float* __restrict__ lkpT,
    const float* __restrict__ gamma, bf16* __restrict__ ab)
{
  int i    = blockIdx.x / 3;
  int hg   = blockIdx.x % 3;
  int lane = threadIdx.x & 63;
  int w    = __builtin_amdgcn_readfirstlane(threadIdx.x >> 6);  // wave id, uniform
  int h    = hg*4 + w;

  __shared__ float lgs[4][S];   // 12 KB

  const float* qrow = q   + ((size_t)h*S + i)*E;   // wave-uniform -> s_load
  const float* lqr  = lqp + ((size_t)h*S + i)*12;  // wave-uniform -> s_load
  const float* wrow = wp  + ((size_t)h*S + i)*S;
  const float* kTh  = kT   + (size_t)h*E*S;
  const float* lkTh = lkpT + (size_t)h*12*S;
  float sf = -0.11785113019775793f * log1pf(__expf(gamma[h]));

  float qv[E];
  #pragma unroll
  for (int e = 0; e < E; ++e) qv[e] = qrow[e];
  float lq[12];
  #pragma unroll
  for (int x = 0; x < 12; ++x) lq[x] = lqr[x];

  float mloc = -1e30f;
  #pragma unroll 2
  for (int jj = 0; jj < 12; ++jj){
    int j = lane + jj*64;
    float d = 0.f;
    #pragma unroll
    for (int e = 0; e < E; ++e) d += qv[e]*kTh[(size_t)e*S + j];
    float fr = 0.f;
    #pragma unroll
    for (int x = 0; x < 12; ++x){ float df = lq[x] - lkTh[(size_t)x*S + j]; fr += df*df; }
    float lg = wrow[j] + 0.25f*d + sf*fr;
    lgs[w][j] = lg;
    mloc = fmaxf(mloc, lg);
  }
  #pragma unroll
  for (int mk = 1; mk < 64; mk <<= 1) mloc = fmaxf(mloc, __shfl_xor(mloc, mk));

  float sum = 0.f;
  #pragma unroll 3
  for (int jj = 0; jj < 12; ++jj){
    int j = lane + jj*64;
    float v = __expf(lgs[w][j] - mloc);
    lgs[w][j] = v;
    sum += v;
  }
  #pragma unroll
  for (int mk = 1; mk < 64; mk <<= 1) sum += __shfl_xor(sum, mk);
  float inv = 1.f/sum;

  size_t base = ((size_t)h*S + i)*S;
  #pragma unroll 3
  for (int jj = 0; jj < 12; ++jj){
    int j = lane + jj*64;
    ab[base + j] = f2b(lgs[w][j]*inv);
  }
}

// ---------------- fused kernel B: k_asum (blocks 0..383) + k_out_sv (384..2687) -
// out_sv v2: lane = output column c (0..47, 40 real + 8 pad), vf2 row read is
// 192 B contiguous (3 lines) per j-pair; ab pair broadcast (1 line). Two
// independent accumulator chains for MLP.
__global__ __launch_bounds__(256) void k_sv_asum(
    const bf16* __restrict__ ab, const unsigned* __restrict__ vf2,
    const float* __restrict__ rot, const float* __restrict__ trans,
    bf16* __restrict__ attnb, float* __restrict__ asumT)
{
  if (blockIdx.x < 384){
    // ---- k_asum body ----
    int h  = blockIdx.x / 32;
    int i0 = (blockIdx.x % 32) * 24;
    int t  = threadIdx.x;
    float a0 = 0.f, a1 = 0.f, a2 = 0.f;
    for (int i = i0; i < i0 + 24; ++i){
      const bf16* row = ab + ((size_t)h*S + i)*S;
      a0 += b2f(row[t]);
      a1 += b2f(row[t + 256]);
      a2 += b2f(row[t + 512]);
    }
    atomicAdd(&asumT[(t      )*H + h], a0);
    atomicAdd(&asumT[(t + 256)*H + h], a1);
    atomicAdd(&asumT[(t + 512)*H + h], a2);
  } else {
    // ---- k_out_sv body ----
    int bid  = blockIdx.x - 384;
    int h    = bid / (S/4);
    int i0   = (bid % (S/4))*4;
    int w    = threadIdx.x >> 6;
    int lane = threadIdx.x & 63;
    int i = i0 + w;
    const unsigned* arow = (const unsigned*)(ab + ((size_t)h*S + i)*S);  // 384 uints
    float acc = 0.f;
    if (lane < 48){
      const unsigned* vrow = vf2 + (size_t)h*(S/2)*48 + lane;
      float acc1 = 0.f;
      #pragma unroll 4
      for (int jp = 0; jp < S/2; jp += 2){
        unsigned ap0 = arow[jp], ap1 = arow[jp+1];
        unsigned vp0 = vrow[(size_t)jp*48], vp1 = vrow[(size_t)(jp+1)*48];
        acc  += blo(ap0)*blo(vp0) + bhi(ap0)*bhi(vp0);
        acc1 += blo(ap1)*blo(vp1) + bhi(ap1)*bhi(vp1);
      }
      acc += acc1;
    }
    __shared__ float ol[4][24];
    __shared__ float ogs[4][24];
    int pd = lane - 16;
    if (lane >= 16 && lane < 40) ol[w][pd] = acc;
    __syncthreads();
    if (lane < 16){
      attnb[(size_t)i*FDIM + h*E + lane] = f2b(acc);
    } else if (lane < 40){
      int p = pd/3, d = pd%3;
      float r0 = rot[(size_t)i*9 + 0 + d];
      float r1 = rot[(size_t)i*9 + 3 + d];
      float r2 = rot[(size_t)i*9 + 6 + d];
      float x0 = ol[w][p*3+0] - trans[i*3+0];
      float x1 = ol[w][p*3+1] - trans[i*3+1];
      float x2 = ol[w][p*3+2] - trans[i*3+2];
      float og = r0*x0 + r1*x1 + r2*x2;
      attnb[(size_t)i*FDIM + OFF_PTS + p*(H*3) + h*3 + d] = f2b(og);
      ogs[w][pd] = og;
    }
    __syncthreads();
    if (lane >= 16 && lane < 40 && (pd % 3) == 0){
      int p = pd/3;
      float g0 = ogs[w][p*3], g1 = ogs[w][p*3+1], g2 = ogs[w][p*3+2];
      attnb[(size_t)i*FDIM + OFF_NORM + p*H + h] = f2b(sqrtf(g0*g0 + g1*g1 + g2*g2));
    }
  }
}

// ---------------- kernel 5: o_pair[i,h,c] = sum_k asum[h,k]*pair[i,k,c] ---------
__global__ __launch_bounds__(512) void k_opair(const float* __restrict__ pair,
                                               const float* __restrict__ asumT,
                                               bf16* __restrict__ attnb)
{
  int i  = blockIdx.x;
  int t  = threadIdx.x;
  int c2 = t & 63;
  int g  = __builtin_amdgcn_readfirstlane(t >> 6);   // wave id 0..7, uniform
  float accx[H], accy[H];
  #pragma unroll
  for (int h = 0; h < H; ++h){ accx[h] = 0.f; accy[h] = 0.f; }
  const float2* prow = (const float2*)(pair + (size_t)i*S*CP) + c2;
  for (int kk = 0; kk < 96; ++kk){
    int kj = g*96 + kk;
    float2 pv = prow[(size_t)kj*64];
    const float* ap = asumT + kj*H;    // uniform -> s_load
    #pragma unroll
    for (int h = 0; h < H; ++h){
      accx[h] += ap[h]*pv.x;
      accy[h] += ap[h]*pv.y;
    }
  }
  __shared__ float part[8][H][CP];   // 48 KB
  #pragma unroll
  for (int h = 0; h < H; ++h)
    ((float2*)part[g][h])[c2] = make_float2(accx[h], accy[h]);
  __syncthreads();
  if (t < CP){
    #pragma unroll
    for (int h = 0; h < H; ++h){
      float s = part[0][h][t] + part[1][h][t] + part[2][h][t] + part[3][h][t]
              + part[4][h][t] + part[5][h][t] + part[6][h][t] + part[7][h][t];
      attnb[(size_t)i*FDIM + OFF_PAIR + h*CP + t] = f2b(s);
    }
  }
}

// ---------------- kernel 6: out += attn @ Wo^T (+bo), split-K x4 ---------------
__global__ __launch_bounds__(384) void k_final(const bf16* __restrict__ attnb,
                                               const float* __restrict__ Wo,
                                               const float* __restrict__ bo,
                                               float* __restrict__ out)
{
  int i0 = blockIdx.x*4;
  int ck = blockIdx.y;                     // 0..3
  int o  = threadIdx.x;
  const float4* wrow = (const float4*)(Wo + (size_t)o*FDIM) + ck*132;
  const unsigned* a0 = (const unsigned*)(attnb + (size_t)i0*FDIM) + ck*264;  // uniform
  const unsigned* a1 = a0 + FDIM/2;
  const unsigned* a2 = a1 + FDIM/2;
  const unsigned* a3 = a2 + FDIM/2;
  float c0=0.f, c1=0.f, c2=0.f, c3=0.f;
  for (int cc = 0; cc < 132; ++cc){
    float4 wv = wrow[cc];
    unsigned u;
    u = a0[cc*2]; c0 += wv.x*blo(u)+wv.y*bhi(u); u = a0[cc*2+1]; c0 += wv.z*blo(u)+wv.w*bhi(u);
    u = a1[cc*2]; c1 += wv.x*blo(u)+wv.y*bhi(u); u = a1[cc*2+1]; c1 += wv.z*blo(u)+wv.w*bhi(u);
    u = a2[cc*2]; c2 += wv.x*blo(u)+wv.y*bhi(u); u = a2[cc*2+1]; c2 += wv.z*blo(u)+wv.w*bhi(u);
    u = a3[cc*2]; c3 += wv.x*blo(u)+wv.y*bhi(u); u = a3[cc*2+1]; c3 += wv.z*blo(u)+wv.w*bhi(u);
  }
  if (ck == 0){
    float b = bo[o];
    c0 += b; c1 += b; c2 += b; c3 += b;
  }
  atomicAdd(&out[(size_t)(i0+0)*CS + o], c0);
  atomicAdd(&out[(size_t)(i0+1)*CS + o], c1);
  atomicAdd(&out[(size_t)(i0+2)*CS + o], c2);
  atomicAdd(&out[(size_t)(i0+3)*CS + o], c3);
}

extern "C" void kernel_launch(void* const* d_in, const int* in_sizes, int n_in,
                              void* d_out, int out_size, void* d_ws, size_t ws_size,
                              hipStream_t stream)
{
  const float* sr    = (const float*)d_in[0];
  const float* pair  = (const float*)d_in[1];
  const float* rot   = (const float*)d_in[2];
  const float* trans = (const float*)d_in[3];
  const float* Wq    = (const float*)d_in[4];
  const float* Wk    = (const float*)d_in[5];
  const float* Wv    = (const float*)d_in[6];
  const float* Wqp   = (const float*)d_in[7];
  const float* Wkp   = (const float*)d_in[8];
  const float* Wvp   = (const float*)d_in[9];
  const float* Wb    = (const float*)d_in[10];
  const float* Wo    = (const float*)d_in[11];
  const float* bo    = (const float*)d_in[12];
  const float* gamma = (const float*)d_in[13];

  // workspace layout (float units)
  float* ws    = (float*)d_ws;
  float*    q     = ws;                          // 147456
  float*    kT    = q    + 147456;               // 147456 [h][e][s]
  float*    lqp   = kT   + 147456;               // 110592 [h][s][12]
  float*    lkpT  = lqp  + 110592;               // 110592 [h][x][s]
  unsigned* vf2   = (unsigned*)(lkpT + 110592);  // 221184 uints [h][jp][48] bf16x2
  float*    asumT = (float*)(vf2 + 221184);      // 9216  [j][h]
  bf16*     ab    = (bf16*)(asumT + 9216);               // H*S*S bf16
  bf16*     attnb = (bf16*)(asumT + 9216 + 3538944);     // S*FDIM bf16
  float*    wp    = asumT + 9216 + 3538944 + 811008;     // H*S*S fp32 logits
  float* out = (float*)d_out;

  hipMemsetAsync(asumT, 0, (size_t)S*H*sizeof(float), stream);
  hipMemsetAsync(out,   0, (size_t)S*CS*sizeof(float), stream);
  k_proj_wpair<<<S/2 + (S*S)/256, 256, 0, stream>>>(sr, rot, trans, Wq, Wk, Wv, Wqp, Wkp, Wvp,
                                                    q, kT, vf2, lqp, lkpT, pair, Wb, wp);
  k_attn      <<<S*3,             256, 0, stream>>>(wp, q, kT, lqp, lkpT, gamma, ab);
  k_sv_asum   <<<384 + H*(S/4),   256, 0, stream>>>(ab, vf2, rot, trans, attnb, asumT);
  k_opair     <<<S,               512, 0, stream>>>(pair, asumT, attnb);
  k_final     <<<dim3(S/4, 4),    384, 0, stream>>>(attnb, Wo, bo, out);
}